// Round 1
// baseline (2690.169 us; speedup 1.0000x reference)
//
#include <hip/hip_runtime.h>

#define SEQ 512
#define HD 512
#define BATCH 32
#define TOK (BATCH * SEQ)   // 16384
#define NHEAD 8
#define DKDIM 64
#define MREL 16
#define NRELV 33

__device__ __forceinline__ int relclamp(int v) {
  return min(max(v, -MREL), MREL) + MREL;
}

// ---------------- positional-encoding table (S x H) ----------------
__global__ __launch_bounds__(256) void pe_kernel(float* __restrict__ PE) {
  const int i = blockIdx.x * 256 + threadIdx.x;   // < SEQ*HD
  const int s = i >> 9, h = i & (HD - 1);
  float v = 0.f;
  if (s > 0) {
    const int i2 = h & ~1;
    const float div = expf((float)i2 * (-9.210340371976184f / (float)HD)); // ln(10000)
    const float ang = (float)(s - 1) * div;
    v = (h & 1) ? cosf(ang) : sinf(ang);
  }
  PE[i] = v;
}

// ---------------- x = x + pe * mask ----------------
__global__ __launch_bounds__(256) void addpos_kernel(
    const float* __restrict__ x, const int* __restrict__ mask,
    const float* __restrict__ PE, float* __restrict__ out) {
  const long i = (long)blockIdx.x * 256 + threadIdx.x;   // < TOK*HD
  const int h = (int)(i & (HD - 1));
  const long bs = i >> 9;
  const int s = (int)(bs & (SEQ - 1));
  out[i] = x[i] + PE[s * HD + h] * (float)mask[bs];
}

// ---------------- LayerNorm, one block per row ----------------
__global__ __launch_bounds__(256) void ln_kernel(
    const float* __restrict__ X, const float* __restrict__ g,
    const float* __restrict__ bta, float* __restrict__ Y) {
  const int row = blockIdx.x;
  const int t = threadIdx.x;
  const float* xr = X + (long)row * HD;
  const float x0 = xr[t], x1 = xr[t + 256];
  float s = x0 + x1, q = x0 * x0 + x1 * x1;
  #pragma unroll
  for (int off = 32; off > 0; off >>= 1) {
    s += __shfl_down(s, off);
    q += __shfl_down(q, off);
  }
  __shared__ float sh[10];
  const int w = t >> 6;
  if ((t & 63) == 0) { sh[w] = s; sh[4 + w] = q; }
  __syncthreads();
  if (t == 0) {
    const float S_ = sh[0] + sh[1] + sh[2] + sh[3];
    const float Q_ = sh[4] + sh[5] + sh[6] + sh[7];
    const float mu = S_ * (1.f / (float)HD);
    const float var = Q_ * (1.f / (float)HD) - mu * mu;
    sh[8] = mu;
    sh[9] = rsqrtf(var + 1e-5f);
  }
  __syncthreads();
  const float mu = sh[8], rstd = sh[9];
  float* yr = Y + (long)row * HD;
  yr[t]       = (x0 - mu) * rstd * g[t] + bta[t];
  yr[t + 256] = (x1 - mu) * rstd * g[t + 256] + bta[t + 256];
}

// ---------------- depthwise conv1d K=7, pad 3 (layout (b,s,c)) ----------------
__global__ __launch_bounds__(256) void dwconv_kernel(
    const float* __restrict__ N_, const float* __restrict__ w,
    const float* __restrict__ bias, float* __restrict__ Hout) {
  const long i = (long)blockIdx.x * 256 + threadIdx.x;   // < TOK*HD
  const int cch = (int)(i & (HD - 1));
  const long bs = i >> 9;
  const int s = (int)(bs & (SEQ - 1));
  const long rowb = bs - s;                               // b*SEQ
  float acc = bias[cch];
  #pragma unroll
  for (int k = 0; k < 7; ++k) {
    const int ss = s + k - 3;
    if (ss >= 0 && ss < SEQ)
      acc += N_[(rowb + ss) * HD + cch] * w[cch * 7 + k];
  }
  Hout[i] = acc;
}

// ---------------- tiled f32 GEMM: C[r,o] (op)= A[r,:] . W[o,:] + bias[o] ---------
// MODE 0: C = G+b   MODE 1: C += G+b   MODE 2: C += relu(G+b)
template <int MODE>
__global__ __launch_bounds__(256) void gemm_kernel(
    const float* __restrict__ A, const float* __restrict__ W,
    const float* __restrict__ bias, float* __restrict__ C) {
  __shared__ float As[16][68];
  __shared__ float Bs[16][68];
  const int t = threadIdx.x;
  const int row0 = blockIdx.y * 64;
  const int col0 = blockIdx.x * 64;
  const int lm = t >> 2;           // 0..63
  const int lk = (t & 3) << 2;     // 0,4,8,12
  const int tm = (t & 15) << 2;    // 0..60
  const int tn = (t >> 4) << 2;    // 0..60
  float acc[4][4] = {};
  for (int kt = 0; kt < HD; kt += 16) {
    const float4 a4 = *(const float4*)&A[(long)(row0 + lm) * HD + kt + lk];
    const float4 b4 = *(const float4*)&W[(long)(col0 + lm) * HD + kt + lk];
    __syncthreads();
    As[lk + 0][lm] = a4.x; As[lk + 1][lm] = a4.y; As[lk + 2][lm] = a4.z; As[lk + 3][lm] = a4.w;
    Bs[lk + 0][lm] = b4.x; Bs[lk + 1][lm] = b4.y; Bs[lk + 2][lm] = b4.z; Bs[lk + 3][lm] = b4.w;
    __syncthreads();
    #pragma unroll
    for (int k = 0; k < 16; ++k) {
      const float4 av = *(const float4*)&As[k][tm];
      const float4 bv = *(const float4*)&Bs[k][tn];
      acc[0][0] += av.x * bv.x; acc[0][1] += av.x * bv.y; acc[0][2] += av.x * bv.z; acc[0][3] += av.x * bv.w;
      acc[1][0] += av.y * bv.x; acc[1][1] += av.y * bv.y; acc[1][2] += av.y * bv.z; acc[1][3] += av.y * bv.w;
      acc[2][0] += av.z * bv.x; acc[2][1] += av.z * bv.y; acc[2][2] += av.z * bv.z; acc[2][3] += av.z * bv.w;
      acc[3][0] += av.w * bv.x; acc[3][1] += av.w * bv.y; acc[3][2] += av.w * bv.z; acc[3][3] += av.w * bv.w;
    }
  }
  const float4 b4 = *(const float4*)&bias[col0 + tn];
  #pragma unroll
  for (int i = 0; i < 4; ++i) {
    float4 gg;
    gg.x = acc[i][0] + b4.x; gg.y = acc[i][1] + b4.y;
    gg.z = acc[i][2] + b4.z; gg.w = acc[i][3] + b4.w;
    float4* cp = (float4*)&C[(long)(row0 + tm + i) * HD + col0 + tn];
    if (MODE == 0) {
      *cp = gg;
    } else {
      float4 cv = *cp;
      if (MODE == 2) {
        gg.x = fmaxf(gg.x, 0.f); gg.y = fmaxf(gg.y, 0.f);
        gg.z = fmaxf(gg.z, 0.f); gg.w = fmaxf(gg.w, 0.f);
      }
      cv.x += gg.x; cv.y += gg.y; cv.z += gg.z; cv.w += gg.w;
      *cp = cv;
    }
  }
}

// ---------------- attention with relative positions ----------------
// One block per (b, head, 16-q-row tile). QK^T + qek term, softmax,
// PV + wsum.embed_v term. K/V staged in XOR-swizzled LDS tiles.
__global__ __launch_bounds__(256) void attn_kernel(
    const float* __restrict__ Qg, const float* __restrict__ Kg,
    const float* __restrict__ Vg, const float* __restrict__ ekg,
    const float* __restrict__ evg, float* __restrict__ Og) {
  __shared__ float qs[16][68];
  __shared__ float kv[64][64];
  __shared__ float ls[16][516];
  __shared__ float qek[16][34];
  __shared__ float evs[NRELV][64];
  __shared__ float wsum[16][34];
  __shared__ float rowred[16][17];

  const int t  = threadIdx.x;
  const int qt = blockIdx.x;       // 0..31
  const int hh = blockIdx.y;       // 0..7
  const int bb = blockIdx.z;       // 0..31
  const int q0 = qt * 16;
  const long base = ((long)bb * SEQ) * HD + hh * DKDIM;

  // stage q rows; ek into kv (temp, plain layout); ev
  for (int i = t; i < 16 * DKDIM; i += 256) {
    const int qi = i >> 6, d = i & 63;
    qs[qi][d] = Qg[base + (long)(q0 + qi) * HD + d];
  }
  for (int i = t; i < NRELV * DKDIM; i += 256) {
    const int r = i >> 6, d = i & 63;
    kv[r][d] = ekg[i];
    evs[r][d] = evg[i];
  }
  __syncthreads();
  // qek[qi][r] = q_row . embed_k[r]
  for (int o = t; o < 16 * NRELV; o += 256) {
    const int qi = o / NRELV, r = o % NRELV;
    float s = 0.f;
    for (int d = 0; d < DKDIM; ++d) s += qs[qi][d] * kv[r][d];
    qek[qi][r] = s;
  }

  const int qi = t >> 4;           // 0..15  (q row within tile)
  const int c16 = t & 15;
  const int kr0 = c16 * 4;         // 4 consecutive k rows in phase 1
  const int qglob = q0 + qi;

  // ---- phase 1: logits ----
  for (int kt = 0; kt < 8; ++kt) {
    __syncthreads();
    for (int i = t; i < 64 * 64; i += 256) {
      const int kr = i >> 6, d = i & 63;
      kv[kr][(((d >> 2) ^ ((kr >> 2) & 15)) << 2) | (d & 3)] =
          Kg[base + (long)(kt * 64 + kr) * HD + d];
    }
    __syncthreads();
    float a0 = 0.f, a1 = 0.f, a2 = 0.f, a3 = 0.f;
    #pragma unroll
    for (int g = 0; g < 16; ++g) {
      const float4 a = *(const float4*)&qs[qi][g * 4];
      const int col = ((g ^ c16) << 2);
      const float4 k0 = *(const float4*)&kv[kr0 + 0][col];
      const float4 k1 = *(const float4*)&kv[kr0 + 1][col];
      const float4 k2 = *(const float4*)&kv[kr0 + 2][col];
      const float4 k3 = *(const float4*)&kv[kr0 + 3][col];
      a0 += a.x * k0.x + a.y * k0.y + a.z * k0.z + a.w * k0.w;
      a1 += a.x * k1.x + a.y * k1.y + a.z * k1.z + a.w * k1.w;
      a2 += a.x * k2.x + a.y * k2.y + a.z * k2.z + a.w * k2.w;
      a3 += a.x * k3.x + a.y * k3.y + a.z * k3.z + a.w * k3.w;
    }
    const int kg = kt * 64 + kr0;
    const int db = kg - qglob;
    float4 lw;
    lw.x = a0 + qek[qi][relclamp(db + 0)];
    lw.y = a1 + qek[qi][relclamp(db + 1)];
    lw.z = a2 + qek[qi][relclamp(db + 2)];
    lw.w = a3 + qek[qi][relclamp(db + 3)];
    *(float4*)&ls[qi][kg] = lw;
  }
  __syncthreads();

  // ---- softmax over 512 keys; 16 threads per row ----
  {
    const int srow = qi, sl = c16;
    float lmax = -3.4e38f;
    for (int k = sl; k < SEQ; k += 16) lmax = fmaxf(lmax, ls[srow][k]);
    rowred[srow][sl] = lmax;
    __syncthreads();
    if (sl == 0) {
      float m = rowred[srow][0];
      for (int j = 1; j < 16; ++j) m = fmaxf(m, rowred[srow][j]);
      rowred[srow][16] = m;
    }
    __syncthreads();
    const float rmax = rowred[srow][16];
    float lsum = 0.f;
    for (int k = sl; k < SEQ; k += 16) {
      const float e = __expf(ls[srow][k] - rmax);
      ls[srow][k] = e;
      lsum += e;
    }
    __syncthreads();
    rowred[srow][sl] = lsum;
    __syncthreads();
    if (sl == 0) {
      float s_ = 0.f;
      for (int j = 0; j < 16; ++j) s_ += rowred[srow][j];
      rowred[srow][16] = s_;
    }
    __syncthreads();
    const float rinv = 1.f / rowred[srow][16];
    for (int k = sl; k < SEQ; k += 16) ls[srow][k] *= rinv;
    __syncthreads();
  }

  // ---- wsum[row][r] = sum of w over keys with rel-bucket r ----
  for (int o = t; o < 16 * NRELV; o += 256) {
    const int row = o / NRELV, r = o % NRELV;
    const int qrow = q0 + row;
    float s = 0.f;
    if (r == 0) {
      const int kend = qrow - MREL;
      for (int k = 0; k <= kend; ++k) s += ls[row][k];
    } else if (r == NRELV - 1) {
      for (int k = qrow + MREL; k < SEQ; ++k) s += ls[row][k];
    } else {
      const int k = qrow + r - MREL;
      if (k >= 0 && k < SEQ) s = ls[row][k];
    }
    wsum[row][r] = s;
  }

  // ---- phase 3: PV ----
  float o0 = 0.f, o1 = 0.f, o2 = 0.f, o3 = 0.f;
  for (int vt = 0; vt < 8; ++vt) {
    __syncthreads();
    for (int i = t; i < 64 * 64; i += 256) {
      const int kr = i >> 6, d = i & 63;
      kv[kr][(((d >> 2) ^ ((kr >> 2) & 15)) << 2) | (d & 3)] =
          Vg[base + (long)(vt * 64 + kr) * HD + d];
    }
    __syncthreads();
    #pragma unroll
    for (int k4 = 0; k4 < 16; ++k4) {
      const float4 w4 = *(const float4*)&ls[qi][vt * 64 + k4 * 4];
      #pragma unroll
      for (int u = 0; u < 4; ++u) {
        const int kl = k4 * 4 + u;
        const float4 v4 = *(const float4*)&kv[kl][((c16 ^ ((kl >> 2) & 15)) << 2)];
        const float wv = (u == 0) ? w4.x : (u == 1) ? w4.y : (u == 2) ? w4.z : w4.w;
        o0 += wv * v4.x; o1 += wv * v4.y; o2 += wv * v4.z; o3 += wv * v4.w;
      }
    }
  }
  // rel_v epilogue: o += wsum . embed_v
  #pragma unroll 1
  for (int r = 0; r < NRELV; ++r) {
    const float wr = wsum[qi][r];
    const float4 e4 = *(const float4*)&evs[r][c16 * 4];
    o0 += wr * e4.x; o1 += wr * e4.y; o2 += wr * e4.z; o3 += wr * e4.w;
  }
  float4 ov; ov.x = o0; ov.y = o1; ov.z = o2; ov.w = o3;
  *(float4*)&Og[base + (long)qglob * HD + c16 * 4] = ov;
}

extern "C" void kernel_launch(void* const* d_in, const int* in_sizes, int n_in,
                              void* d_out, int out_size, void* d_ws, size_t ws_size,
                              hipStream_t stream) {
  const float* x    = (const float*)d_in[0];
  const int*   mask = (const int*)d_in[1];
  const float* dw_w = (const float*)d_in[2];
  const float* dw_b = (const float*)d_in[3];
  const float* pw_w = (const float*)d_in[4];
  const float* pw_b = (const float*)d_in[5];
  const float* lncg = (const float*)d_in[6];
  const float* lncb = (const float*)d_in[7];
  const float* wq   = (const float*)d_in[8];
  const float* bq   = (const float*)d_in[9];
  const float* wk   = (const float*)d_in[10];
  const float* bk   = (const float*)d_in[11];
  const float* wv   = (const float*)d_in[12];
  const float* bv   = (const float*)d_in[13];
  const float* wo   = (const float*)d_in[14];
  const float* bo   = (const float*)d_in[15];
  const float* ek   = (const float*)d_in[16];
  const float* ev   = (const float*)d_in[17];
  const float* lnag = (const float*)d_in[18];
  const float* lnab = (const float*)d_in[19];
  const float* wff  = (const float*)d_in[20];
  const float* bff  = (const float*)d_in[21];
  const float* lnfg = (const float*)d_in[22];
  const float* lnfb = (const float*)d_in[23];

  float* out = (float*)d_out;
  float* PE = (float*)d_ws;                 // SEQ*HD
  float* NB = PE + SEQ * HD;                // TOK*HD  (LN out / attn O)
  float* QB = NB + (long)TOK * HD;          // TOK*HD  (conv h / Q)
  float* KB = QB + (long)TOK * HD;
  float* VB = KB + (long)TOK * HD;

  pe_kernel<<<SEQ * HD / 256, 256, 0, stream>>>(PE);
  addpos_kernel<<<TOK * HD / 256, 256, 0, stream>>>(x, mask, PE, out);

  for (int i = 0; i < 2; ++i) {
    ln_kernel<<<TOK, 256, 0, stream>>>(out, lncg + i * HD, lncb + i * HD, NB);
    dwconv_kernel<<<TOK * HD / 256, 256, 0, stream>>>(NB, dw_w + i * HD * 7, dw_b + i * HD, QB);
    gemm_kernel<2><<<dim3(HD / 64, TOK / 64), 256, 0, stream>>>(QB, pw_w + (long)i * HD * HD, pw_b + i * HD, out);
  }

  ln_kernel<<<TOK, 256, 0, stream>>>(out, lnag, lnab, NB);
  gemm_kernel<0><<<dim3(HD / 64, TOK / 64), 256, 0, stream>>>(NB, wq, bq, QB);
  gemm_kernel<0><<<dim3(HD / 64, TOK / 64), 256, 0, stream>>>(NB, wk, bk, KB);
  gemm_kernel<0><<<dim3(HD / 64, TOK / 64), 256, 0, stream>>>(NB, wv, bv, VB);
  attn_kernel<<<dim3(SEQ / 16, NHEAD, BATCH), 256, 0, stream>>>(QB, KB, VB, ek, ev, NB);
  gemm_kernel<1><<<dim3(HD / 64, TOK / 64), 256, 0, stream>>>(NB, wo, bo, out);

  ln_kernel<<<TOK, 256, 0, stream>>>(out, lnfg, lnfb, NB);
  gemm_kernel<2><<<dim3(HD / 64, TOK / 64), 256, 0, stream>>>(NB, wff, bff, out);
}

// Round 2
// 1275.428 us; speedup vs baseline: 2.1092x; 2.1092x over previous
//
#include <hip/hip_runtime.h>

#define SEQ 512
#define HD 512
#define BATCH 32
#define TOK (BATCH * SEQ)   // 16384
#define NHEAD 8
#define DKDIM 64
#define MREL 16
#define NRELV 33

using short8 = __attribute__((ext_vector_type(8))) short;
using f32x4  = __attribute__((ext_vector_type(4))) float;

__device__ __forceinline__ int relclamp(int v) {
  return min(max(v, -MREL), MREL) + MREL;
}

__device__ __forceinline__ unsigned short f2bf(float x) {
  union { float f; unsigned u; } c; c.f = x;
  unsigned r = c.u + 0x7FFF + ((c.u >> 16) & 1);
  return (unsigned short)(r >> 16);
}

// swizzled byte offset within a 128B-row 2D LDS tile (T2: break 16-way conflicts)
#define SWZ(row, byte) ((row) * 128 + ((byte) ^ (((row) & 7) << 4)))

// ---------------- positional-encoding table (S x H) ----------------
__global__ __launch_bounds__(256) void pe_kernel(float* __restrict__ PE) {
  const int i = blockIdx.x * 256 + threadIdx.x;   // < SEQ*HD
  const int s = i >> 9, h = i & (HD - 1);
  float v = 0.f;
  if (s > 0) {
    const int i2 = h & ~1;
    const float div = expf((float)i2 * (-9.210340371976184f / (float)HD)); // ln(10000)
    const float ang = (float)(s - 1) * div;
    v = (h & 1) ? cosf(ang) : sinf(ang);
  }
  PE[i] = v;
}

// ---------------- x = x + pe * mask ----------------
__global__ __launch_bounds__(256) void addpos_kernel(
    const float* __restrict__ x, const int* __restrict__ mask,
    const float* __restrict__ PE, float* __restrict__ out) {
  const long i = (long)blockIdx.x * 256 + threadIdx.x;   // < TOK*HD
  const int h = (int)(i & (HD - 1));
  const long bs = i >> 9;
  const int s = (int)(bs & (SEQ - 1));
  out[i] = x[i] + PE[s * HD + h] * (float)mask[bs];
}

// ---------------- LayerNorm, one block per row ----------------
__global__ __launch_bounds__(256) void ln_kernel(
    const float* __restrict__ X, const float* __restrict__ g,
    const float* __restrict__ bta, float* __restrict__ Y) {
  const int row = blockIdx.x;
  const int t = threadIdx.x;
  const float* xr = X + (long)row * HD;
  const float x0 = xr[t], x1 = xr[t + 256];
  float s = x0 + x1, q = x0 * x0 + x1 * x1;
  #pragma unroll
  for (int off = 32; off > 0; off >>= 1) {
    s += __shfl_down(s, off);
    q += __shfl_down(q, off);
  }
  __shared__ float sh[10];
  const int w = t >> 6;
  if ((t & 63) == 0) { sh[w] = s; sh[4 + w] = q; }
  __syncthreads();
  if (t == 0) {
    const float S_ = sh[0] + sh[1] + sh[2] + sh[3];
    const float Q_ = sh[4] + sh[5] + sh[6] + sh[7];
    const float mu = S_ * (1.f / (float)HD);
    const float var = Q_ * (1.f / (float)HD) - mu * mu;
    sh[8] = mu;
    sh[9] = rsqrtf(var + 1e-5f);
  }
  __syncthreads();
  const float mu = sh[8], rstd = sh[9];
  float* yr = Y + (long)row * HD;
  yr[t]       = (x0 - mu) * rstd * g[t] + bta[t];
  yr[t + 256] = (x1 - mu) * rstd * g[t + 256] + bta[t + 256];
}

// ---------------- depthwise conv1d K=7, pad 3 (layout (b,s,c)) ----------------
__global__ __launch_bounds__(256) void dwconv_kernel(
    const float* __restrict__ N_, const float* __restrict__ w,
    const float* __restrict__ bias, float* __restrict__ Hout) {
  const long i = (long)blockIdx.x * 256 + threadIdx.x;   // < TOK*HD
  const int cch = (int)(i & (HD - 1));
  const long bs = i >> 9;
  const int s = (int)(bs & (SEQ - 1));
  const long rowb = bs - s;                               // b*SEQ
  float acc = bias[cch];
  #pragma unroll
  for (int k = 0; k < 7; ++k) {
    const int ss = s + k - 3;
    if (ss >= 0 && ss < SEQ)
      acc += N_[(rowb + ss) * HD + cch] * w[cch * 7 + k];
  }
  Hout[i] = acc;
}

// ---------------- tiled f32 GEMM: C[r,o] (op)= A[r,:] . W[o,:] + bias[o] ---------
// MODE 0: C = G+b   MODE 1: C += G+b   MODE 2: C += relu(G+b)
template <int MODE>
__global__ __launch_bounds__(256) void gemm_kernel(
    const float* __restrict__ A, const float* __restrict__ W,
    const float* __restrict__ bias, float* __restrict__ C) {
  __shared__ float As[16][68];
  __shared__ float Bs[16][68];
  const int t = threadIdx.x;
  const int row0 = blockIdx.y * 64;
  const int col0 = blockIdx.x * 64;
  const int lm = t >> 2;           // 0..63
  const int lk = (t & 3) << 2;     // 0,4,8,12
  const int tm = (t & 15) << 2;    // 0..60
  const int tn = (t >> 4) << 2;    // 0..60
  float acc[4][4] = {};
  for (int kt = 0; kt < HD; kt += 16) {
    const float4 a4 = *(const float4*)&A[(long)(row0 + lm) * HD + kt + lk];
    const float4 b4 = *(const float4*)&W[(long)(col0 + lm) * HD + kt + lk];
    __syncthreads();
    As[lk + 0][lm] = a4.x; As[lk + 1][lm] = a4.y; As[lk + 2][lm] = a4.z; As[lk + 3][lm] = a4.w;
    Bs[lk + 0][lm] = b4.x; Bs[lk + 1][lm] = b4.y; Bs[lk + 2][lm] = b4.z; Bs[lk + 3][lm] = b4.w;
    __syncthreads();
    #pragma unroll
    for (int k = 0; k < 16; ++k) {
      const float4 av = *(const float4*)&As[k][tm];
      const float4 bv = *(const float4*)&Bs[k][tn];
      acc[0][0] += av.x * bv.x; acc[0][1] += av.x * bv.y; acc[0][2] += av.x * bv.z; acc[0][3] += av.x * bv.w;
      acc[1][0] += av.y * bv.x; acc[1][1] += av.y * bv.y; acc[1][2] += av.y * bv.z; acc[1][3] += av.y * bv.w;
      acc[2][0] += av.z * bv.x; acc[2][1] += av.z * bv.y; acc[2][2] += av.z * bv.z; acc[2][3] += av.z * bv.w;
      acc[3][0] += av.w * bv.x; acc[3][1] += av.w * bv.y; acc[3][2] += av.w * bv.z; acc[3][3] += av.w * bv.w;
    }
  }
  const float4 b4 = *(const float4*)&bias[col0 + tn];
  #pragma unroll
  for (int i = 0; i < 4; ++i) {
    float4 gg;
    gg.x = acc[i][0] + b4.x; gg.y = acc[i][1] + b4.y;
    gg.z = acc[i][2] + b4.z; gg.w = acc[i][3] + b4.w;
    float4* cp = (float4*)&C[(long)(row0 + tm + i) * HD + col0 + tn];
    if (MODE == 0) {
      *cp = gg;
    } else {
      float4 cv = *cp;
      if (MODE == 2) {
        gg.x = fmaxf(gg.x, 0.f); gg.y = fmaxf(gg.y, 0.f);
        gg.z = fmaxf(gg.z, 0.f); gg.w = fmaxf(gg.w, 0.f);
      }
      cv.x += gg.x; cv.y += gg.y; cv.z += gg.z; cv.w += gg.w;
      *cp = cv;
    }
  }
}

// ---------------- MFMA bf16 attention with relative positions ----------------
// Block = 4 waves, 32 q-rows. K-tiles of 64 keys. No-max softmax (logits
// bounded ~13), full unnormalized accumulation, normalize at epilogue.
// Shaw rel-k via qek[32][33]; rel-v via bucket sums wsum[32][33].
__global__ __launch_bounds__(256) void attn_kernel(
    const float* __restrict__ Qg, const float* __restrict__ Kg,
    const float* __restrict__ Vg, const float* __restrict__ ekg,
    const float* __restrict__ evg, float* __restrict__ Og) {
  __shared__ char QS[32 * 128];        // Q tile bf16, swizzled
  __shared__ char KV[64 * 128];        // K tile, then V^T tile, bf16 swizzled
  __shared__ char PS[32 * 128];        // P tile bf16, swizzled
  __shared__ float QEK[32][NRELV];
  __shared__ float WS[32][NRELV];
  __shared__ float LROW[32];
  __shared__ float EKs[NRELV][64];
  __shared__ float EVs[NRELV][64];

  const int t = threadIdx.x;
  const int q0 = blockIdx.x * 32;
  const long base = ((long)blockIdx.z * SEQ) * HD + blockIdx.y * DKDIM;

  // ---- prologue: stage Q (bf16 swz), ek/ev (f32), zero accumulators ----
  #pragma unroll
  for (int it = 0; it < 2; ++it) {
    const int idx = t + it * 256;            // 512 float4s
    const int row = idx >> 4, c4 = idx & 15;
    const float4 v = *(const float4*)&Qg[base + (long)(q0 + row) * HD + c4 * 4];
    const unsigned px = (unsigned)f2bf(v.x) | ((unsigned)f2bf(v.y) << 16);
    const unsigned py = (unsigned)f2bf(v.z) | ((unsigned)f2bf(v.w) << 16);
    *(uint2*)(QS + SWZ(row, c4 * 8)) = make_uint2(px, py);
  }
  for (int i = t; i < NRELV * 64; i += 256) {
    EKs[i >> 6][i & 63] = ekg[i];
    EVs[i >> 6][i & 63] = evg[i];
  }
  for (int i = t; i < 32 * NRELV; i += 256) ((float*)WS)[i] = 0.f;
  if (t < 32) LROW[t] = 0.f;
  __syncthreads();

  // ---- qek[m][r] = Q[m,:] . ek[r,:] ----
  for (int o = t; o < 32 * NRELV; o += 256) {
    const int m = o & 31, r = o >> 5;
    float s = 0.f;
    for (int d = 0; d < 64; ++d) {
      const unsigned short qh = *(const unsigned short*)(QS + SWZ(m, d * 2));
      union { unsigned u; float f; } cv; cv.u = (unsigned)qh << 16;
      s += cv.f * EKs[r][d];
    }
    QEK[m][r] = s;
  }

  const int lane = t & 63, w = t >> 6;
  const int wr = w >> 1, wc = w & 1;         // wave's rows wr*16.., cols wc*32..
  const int l15 = lane & 15, lhi = lane >> 4;

  __syncthreads();
  // cache Q A-fragments (constant across K-tiles): k-chunk kk: bytes kk*64 + lhi*16
  short8 qa[2];
  qa[0] = *(const short8*)(QS + SWZ(wr * 16 + l15, lhi * 16));
  qa[1] = *(const short8*)(QS + SWZ(wr * 16 + l15, 64 + lhi * 16));

  f32x4 oacc[2] = {};   // O rows wr*16+lhi*4+reg, cols wc*32 + nf*16 + l15

  for (int kt = 0; kt < 8; ++kt) {
    const int k0t = kt * 64;
    __syncthreads();                          // S1: prev PV done with KV/PS
    // stage K tile (64x64) bf16 swizzled
    #pragma unroll
    for (int it = 0; it < 4; ++it) {
      const int idx = t + it * 256;           // 1024 float4s
      const int row = idx >> 4, c4 = idx & 15;
      const float4 v = *(const float4*)&Kg[base + (long)(k0t + row) * HD + c4 * 4];
      const unsigned px = (unsigned)f2bf(v.x) | ((unsigned)f2bf(v.y) << 16);
      const unsigned py = (unsigned)f2bf(v.z) | ((unsigned)f2bf(v.w) << 16);
      *(uint2*)(KV + SWZ(row, c4 * 8)) = make_uint2(px, py);
    }
    __syncthreads();                          // S2: K ready
    // QK^T: S[m][key] — wave computes 16x32
    f32x4 sacc[2] = {};
    #pragma unroll
    for (int kk = 0; kk < 2; ++kk) {
      const short8 b0 = *(const short8*)(KV + SWZ(wc * 32 + l15,      kk * 64 + lhi * 16));
      const short8 b1 = *(const short8*)(KV + SWZ(wc * 32 + 16 + l15, kk * 64 + lhi * 16));
      sacc[0] = __builtin_amdgcn_mfma_f32_16x16x32_bf16(qa[kk], b0, sacc[0], 0, 0, 0);
      sacc[1] = __builtin_amdgcn_mfma_f32_16x16x32_bf16(qa[kk], b1, sacc[1], 0, 0, 0);
    }
    // exp, P write, wsum buckets, row sums
    #pragma unroll
    for (int reg = 0; reg < 4; ++reg) {
      const int m = wr * 16 + lhi * 4 + reg;
      const int dbase = k0t + wc * 32 - (q0 + m);       // db at wave's key 0
      const bool uniHi = (dbase >= MREL + 1);
      const bool uniLo = (dbase + 31 <= -(MREL + 1));
      float rp = 0.f;
      #pragma unroll
      for (int nf = 0; nf < 2; ++nf) {
        const int keyl = wc * 32 + nf * 16 + l15;
        const int db = dbase + nf * 16 + l15;
        const float s = sacc[nf][reg] + QEK[m][relclamp(db)];
        const float p = __expf(s);
        *(unsigned short*)(PS + SWZ(m, keyl * 2)) = f2bf(p);
        if (!uniHi && !uniLo) atomicAdd(&WS[m][relclamp(db)], p);
        rp += p;
      }
      rp += __shfl_xor(rp, 1); rp += __shfl_xor(rp, 2);
      rp += __shfl_xor(rp, 4); rp += __shfl_xor(rp, 8);
      if (l15 == 0) {
        atomicAdd(&LROW[m], rp);
        if (uniHi)      atomicAdd(&WS[m][2 * MREL], rp);
        else if (uniLo) atomicAdd(&WS[m][0], rp);
      }
    }
    __syncthreads();                          // S3: P ready; K reads done
    // stage V^T tile (Vt[d][key]) bf16 swizzled into KV
    #pragma unroll
    for (int it = 0; it < 4; ++it) {
      const int idx = t + it * 256;
      const int row = idx >> 4, c4 = idx & 15;
      const float4 v = *(const float4*)&Vg[base + (long)(k0t + row) * HD + c4 * 4];
      *(unsigned short*)(KV + SWZ(c4 * 4 + 0, row * 2)) = f2bf(v.x);
      *(unsigned short*)(KV + SWZ(c4 * 4 + 1, row * 2)) = f2bf(v.y);
      *(unsigned short*)(KV + SWZ(c4 * 4 + 2, row * 2)) = f2bf(v.z);
      *(unsigned short*)(KV + SWZ(c4 * 4 + 3, row * 2)) = f2bf(v.w);
    }
    __syncthreads();                          // S4: V^T ready
    // PV: O[m][d] += P[m][k] * Vt[d][k]
    #pragma unroll
    for (int kk = 0; kk < 2; ++kk) {
      const short8 pa = *(const short8*)(PS + SWZ(wr * 16 + l15, kk * 64 + lhi * 16));
      const short8 v0 = *(const short8*)(KV + SWZ(wc * 32 + l15,      kk * 64 + lhi * 16));
      const short8 v1 = *(const short8*)(KV + SWZ(wc * 32 + 16 + l15, kk * 64 + lhi * 16));
      oacc[0] = __builtin_amdgcn_mfma_f32_16x16x32_bf16(pa, v0, oacc[0], 0, 0, 0);
      oacc[1] = __builtin_amdgcn_mfma_f32_16x16x32_bf16(pa, v1, oacc[1], 0, 0, 0);
    }
  }

  // ---- epilogue: rel_v bucket matvec + normalize + write ----
  float rv0[4] = {}, rv1[4] = {};
  const int d0 = wc * 32 + l15, d1 = d0 + 16;
  for (int r = 0; r < NRELV; ++r) {
    const float e0 = EVs[r][d0], e1 = EVs[r][d1];
    #pragma unroll
    for (int reg = 0; reg < 4; ++reg) {
      const float wsr = WS[wr * 16 + lhi * 4 + reg][r];
      rv0[reg] += wsr * e0;
      rv1[reg] += wsr * e1;
    }
  }
  #pragma unroll
  for (int reg = 0; reg < 4; ++reg) {
    const int m = wr * 16 + lhi * 4 + reg;
    const float rinv = 1.f / LROW[m];
    Og[base + (long)(q0 + m) * HD + d0] = (oacc[0][reg] + rv0[reg]) * rinv;
    Og[base + (long)(q0 + m) * HD + d1] = (oacc[1][reg] + rv1[reg]) * rinv;
  }
}

extern "C" void kernel_launch(void* const* d_in, const int* in_sizes, int n_in,
                              void* d_out, int out_size, void* d_ws, size_t ws_size,
                              hipStream_t stream) {
  const float* x    = (const float*)d_in[0];
  const int*   mask = (const int*)d_in[1];
  const float* dw_w = (const float*)d_in[2];
  const float* dw_b = (const float*)d_in[3];
  const float* pw_w = (const float*)d_in[4];
  const float* pw_b = (const float*)d_in[5];
  const float* lncg = (const float*)d_in[6];
  const float* lncb = (const float*)d_in[7];
  const float* wq   = (const float*)d_in[8];
  const float* bq   = (const float*)d_in[9];
  const float* wk   = (const float*)d_in[10];
  const float* bk   = (const float*)d_in[11];
  const float* wv   = (const float*)d_in[12];
  const float* bv   = (const float*)d_in[13];
  const float* wo   = (const float*)d_in[14];
  const float* bo   = (const float*)d_in[15];
  const float* ek   = (const float*)d_in[16];
  const float* ev   = (const float*)d_in[17];
  const float* lnag = (const float*)d_in[18];
  const float* lnab = (const float*)d_in[19];
  const float* wff  = (const float*)d_in[20];
  const float* bff  = (const float*)d_in[21];
  const float* lnfg = (const float*)d_in[22];
  const float* lnfb = (const float*)d_in[23];

  float* out = (float*)d_out;
  float* PE = (float*)d_ws;                 // SEQ*HD
  float* NB = PE + SEQ * HD;                // TOK*HD  (LN out / attn O)
  float* QB = NB + (long)TOK * HD;          // TOK*HD  (conv h / Q)
  float* KB = QB + (long)TOK * HD;
  float* VB = KB + (long)TOK * HD;

  pe_kernel<<<SEQ * HD / 256, 256, 0, stream>>>(PE);
  addpos_kernel<<<TOK * HD / 256, 256, 0, stream>>>(x, mask, PE, out);

  for (int i = 0; i < 2; ++i) {
    ln_kernel<<<TOK, 256, 0, stream>>>(out, lncg + i * HD, lncb + i * HD, NB);
    dwconv_kernel<<<TOK * HD / 256, 256, 0, stream>>>(NB, dw_w + i * HD * 7, dw_b + i * HD, QB);
    gemm_kernel<2><<<dim3(HD / 64, TOK / 64), 256, 0, stream>>>(QB, pw_w + (long)i * HD * HD, pw_b + i * HD, out);
  }

  ln_kernel<<<TOK, 256, 0, stream>>>(out, lnag, lnab, NB);
  gemm_kernel<0><<<dim3(HD / 64, TOK / 64), 256, 0, stream>>>(NB, wq, bq, QB);
  gemm_kernel<0><<<dim3(HD / 64, TOK / 64), 256, 0, stream>>>(NB, wk, bk, KB);
  gemm_kernel<0><<<dim3(HD / 64, TOK / 64), 256, 0, stream>>>(NB, wv, bv, VB);
  attn_kernel<<<dim3(SEQ / 32, NHEAD, BATCH), 256, 0, stream>>>(QB, KB, VB, ek, ev, NB);
  gemm_kernel<1><<<dim3(HD / 64, TOK / 64), 256, 0, stream>>>(NB, wo, bo, out);

  ln_kernel<<<TOK, 256, 0, stream>>>(out, lnfg, lnfb, NB);
  gemm_kernel<2><<<dim3(HD / 64, TOK / 64), 256, 0, stream>>>(NB, wff, bff, out);
}

// Round 3
// 509.500 us; speedup vs baseline: 5.2800x; 2.5033x over previous
//
#include <hip/hip_runtime.h>

#define SEQ 512
#define HD 512
#define BATCH 32
#define TOK (BATCH * SEQ)   // 16384
#define NHEAD 8
#define DKDIM 64
#define MREL 16
#define NRELV 33

using short8 = __attribute__((ext_vector_type(8))) short;
using f32x4  = __attribute__((ext_vector_type(4))) float;
typedef unsigned short ushortT;

#define AS1 __attribute__((address_space(1)))
#define AS3 __attribute__((address_space(3)))
#define GLDS16(g, l) __builtin_amdgcn_global_load_lds( \
    (const AS1 unsigned int*)(const void*)(g), \
    (AS3 unsigned int*)(void*)(l), 16, 0, 0)

__device__ __forceinline__ int relclamp(int v) {
  return min(max(v, -MREL), MREL) + MREL;
}

__device__ __forceinline__ ushortT f2bf(float x) {
  union { float f; unsigned u; } c; c.f = x;
  unsigned r = c.u + 0x7FFF + ((c.u >> 16) & 1);
  return (ushortT)(r >> 16);
}

__device__ __forceinline__ float bf2f(ushortT h) {
  union { unsigned u; float f; } c; c.u = (unsigned)h << 16;
  return c.f;
}

// swizzled byte offset within a 128B-row 2D LDS tile (T2: break 16-way conflicts)
#define SWZ(row, byte) ((row) * 128 + ((byte) ^ (((row) & 7) << 4)))

// ---------------- positional-encoding table (S x H) ----------------
__global__ __launch_bounds__(256) void pe_kernel(float* __restrict__ PE) {
  const int i = blockIdx.x * 256 + threadIdx.x;   // < SEQ*HD
  const int s = i >> 9, h = i & (HD - 1);
  float v = 0.f;
  if (s > 0) {
    const int i2 = h & ~1;
    const float div = expf((float)i2 * (-9.210340371976184f / (float)HD)); // ln(10000)
    const float ang = (float)(s - 1) * div;
    v = (h & 1) ? cosf(ang) : sinf(ang);
  }
  PE[i] = v;
}

// ---------------- x = x + pe * mask ----------------
__global__ __launch_bounds__(256) void addpos_kernel(
    const float* __restrict__ x, const int* __restrict__ mask,
    const float* __restrict__ PE, float* __restrict__ out) {
  const long i = (long)blockIdx.x * 256 + threadIdx.x;   // < TOK*HD
  const int h = (int)(i & (HD - 1));
  const long bs = i >> 9;
  const int s = (int)(bs & (SEQ - 1));
  out[i] = x[i] + PE[s * HD + h] * (float)mask[bs];
}

// ---------------- weights f32 -> bf16 (7 matrices of HD*HD) ----------------
__global__ __launch_bounds__(256) void convw_kernel(
    const float* __restrict__ s0, const float* __restrict__ s1,
    const float* __restrict__ s2, const float* __restrict__ s3,
    const float* __restrict__ s4, const float* __restrict__ s5,
    const float* __restrict__ s6, ushortT* __restrict__ dst) {
  const int i = blockIdx.x * 256 + threadIdx.x;     // < 7 * HD*HD/4
  const int region = i >> 16;                        // HD*HD/4 = 65536
  const int off = i & 65535;
  const float* s = region == 0 ? s0 : region == 1 ? s1 : region == 2 ? s2 :
                   region == 3 ? s3 : region == 4 ? s4 : region == 5 ? s5 : s6;
  const float4 v = ((const float4*)s)[off];
  ushort4 o;
  o.x = f2bf(v.x); o.y = f2bf(v.y); o.z = f2bf(v.z); o.w = f2bf(v.w);
  *(ushort4*)&dst[(long)i * 4] = o;
}

// ---------------- LayerNorm, one block per row; BF: bf16 out ----------------
template <bool BF>
__global__ __launch_bounds__(256) void ln_kernel(
    const float* __restrict__ X, const float* __restrict__ g,
    const float* __restrict__ bta, void* __restrict__ Yv) {
  const int row = blockIdx.x;
  const int t = threadIdx.x;
  const float* xr = X + (long)row * HD;
  const float x0 = xr[t], x1 = xr[t + 256];
  float s = x0 + x1, q = x0 * x0 + x1 * x1;
  #pragma unroll
  for (int off = 32; off > 0; off >>= 1) {
    s += __shfl_down(s, off);
    q += __shfl_down(q, off);
  }
  __shared__ float sh[10];
  const int w = t >> 6;
  if ((t & 63) == 0) { sh[w] = s; sh[4 + w] = q; }
  __syncthreads();
  if (t == 0) {
    const float S_ = sh[0] + sh[1] + sh[2] + sh[3];
    const float Q_ = sh[4] + sh[5] + sh[6] + sh[7];
    const float mu = S_ * (1.f / (float)HD);
    const float var = Q_ * (1.f / (float)HD) - mu * mu;
    sh[8] = mu;
    sh[9] = rsqrtf(var + 1e-5f);
  }
  __syncthreads();
  const float mu = sh[8], rstd = sh[9];
  const float y0 = (x0 - mu) * rstd * g[t] + bta[t];
  const float y1 = (x1 - mu) * rstd * g[t + 256] + bta[t + 256];
  if (BF) {
    ushortT* yr = (ushortT*)Yv + (long)row * HD;
    yr[t] = f2bf(y0);
    yr[t + 256] = f2bf(y1);
  } else {
    float* yr = (float*)Yv + (long)row * HD;
    yr[t] = y0;
    yr[t + 256] = y1;
  }
}

// ---------------- depthwise conv1d K=7, pad 3, bf16 out ----------------
__global__ __launch_bounds__(256) void dwconv_kernel(
    const float* __restrict__ N_, const float* __restrict__ w,
    const float* __restrict__ bias, ushortT* __restrict__ Hout) {
  const long i = (long)blockIdx.x * 256 + threadIdx.x;   // < TOK*HD
  const int cch = (int)(i & (HD - 1));
  const long bs = i >> 9;
  const int s = (int)(bs & (SEQ - 1));
  const long rowb = bs - s;                               // b*SEQ
  float acc = bias[cch];
  #pragma unroll
  for (int k = 0; k < 7; ++k) {
    const int ss = s + k - 3;
    if (ss >= 0 && ss < SEQ)
      acc += N_[(rowb + ss) * HD + cch] * w[cch * 7 + k];
  }
  Hout[i] = f2bf(acc);
}

// ---------------- bf16 MFMA GEMM: G[r,c] = A[r,:] . W[c,:] + bias[c] ----------
// 128x128 tile, BK=32, 4 waves (2x2), global_load_lds staging.
// MODE 0: C=G  1: C+=G  2: C+=relu(G)  3: Cb=bf16(G)  4: Cb=V^T bf16(G)
template <int MODE>
__global__ __launch_bounds__(256) void mgemm_kernel(
    const ushortT* __restrict__ A, const ushortT* __restrict__ W,
    const float* __restrict__ bias, float* __restrict__ C,
    ushortT* __restrict__ Cb) {
  __shared__ ushortT Als[128 * 32];
  __shared__ ushortT Bls[128 * 32];
  const int t = threadIdx.x;
  const int bid = blockIdx.x;                    // 512 blocks
  const int m_blk = (bid & 7) * 16 + ((bid >> 3) & 15);  // XCD-chunked
  const int n_blk = bid >> 7;
  const int row0 = m_blk * 128;
  const int col0 = n_blk * 128;
  const int lane = t & 63, w = t >> 6;
  const int wr = w >> 1, wc = w & 1;
  const int l15 = lane & 15, lhi = lane >> 4;

  f32x4 acc[4][4] = {};

  for (int kt = 0; kt < 16; ++kt) {
    __syncthreads();
    #pragma unroll
    for (int i = 0; i < 2; ++i) {
      const int tl = i * 256 + t;
      const int r = tl >> 2, ch = tl & 3;        // row, 16B chunk
      GLDS16(A + (long)(row0 + r) * HD + kt * 32 + ch * 8,
             Als + (i * 256 + w * 64) * 8);
      GLDS16(W + (long)(col0 + r) * HD + kt * 32 + ch * 8,
             Bls + (i * 256 + w * 64) * 8);
    }
    __syncthreads();
    short8 af[4], bf[4];
    #pragma unroll
    for (int i = 0; i < 4; ++i) {
      af[i] = *(const short8*)&Als[(wr * 64 + i * 16 + l15) * 32 + lhi * 8];
      bf[i] = *(const short8*)&Bls[(wc * 64 + i * 16 + l15) * 32 + lhi * 8];
    }
    #pragma unroll
    for (int mi = 0; mi < 4; ++mi)
      #pragma unroll
      for (int ni = 0; ni < 4; ++ni)
        acc[mi][ni] = __builtin_amdgcn_mfma_f32_16x16x32_bf16(af[mi], bf[ni], acc[mi][ni], 0, 0, 0);
  }

  #pragma unroll
  for (int ni = 0; ni < 4; ++ni) {
    const int c = col0 + wc * 64 + ni * 16 + l15;
    const float bz = bias[c];
    #pragma unroll
    for (int mi = 0; mi < 4; ++mi) {
      if (MODE == 4) {
        const int tok0 = row0 + wr * 64 + mi * 16 + lhi * 4;
        const int b = tok0 >> 9, s = tok0 & (SEQ - 1);
        const int h = c >> 6, d = c & 63;
        ushort4 pk;
        pk.x = f2bf(acc[mi][ni][0] + bz);
        pk.y = f2bf(acc[mi][ni][1] + bz);
        pk.z = f2bf(acc[mi][ni][2] + bz);
        pk.w = f2bf(acc[mi][ni][3] + bz);
        *(ushort4*)&Cb[((long)((b * NHEAD + h) * DKDIM + d) << 9) + s] = pk;
      } else {
        #pragma unroll
        for (int reg = 0; reg < 4; ++reg) {
          const int rrow = row0 + wr * 64 + mi * 16 + lhi * 4 + reg;
          const float g = acc[mi][ni][reg] + bz;
          const long idx = (long)rrow * HD + c;
          if (MODE == 0)      C[idx] = g;
          else if (MODE == 1) C[idx] += g;
          else if (MODE == 2) C[idx] += fmaxf(g, 0.f);
          else                Cb[idx] = f2bf(g);
        }
      }
    }
  }
}

// ---------------- MFMA bf16 attention with relative positions ----------------
// Inputs: Q,K bf16 [token][ch]; Vt bf16 [b,h,d][s]; output O bf16 [token][ch].
__global__ __launch_bounds__(256) void attn_kernel(
    const ushortT* __restrict__ Qg, const ushortT* __restrict__ Kg,
    const ushortT* __restrict__ Vt, const float* __restrict__ ekg,
    const float* __restrict__ evg, ushortT* __restrict__ Og) {
  __shared__ char QS[32 * 128];        // Q tile bf16, swizzled
  __shared__ char KV[64 * 128];        // K tile, then V^T tile, bf16 swizzled
  __shared__ char PS[32 * 128];        // P tile bf16, swizzled
  __shared__ float QEK[32][NRELV];
  __shared__ float WS[32][NRELV];
  __shared__ float LROW[32];
  __shared__ float EKs[NRELV][64];
  __shared__ float EVs[NRELV][64];

  const int t = threadIdx.x;
  const int q0 = blockIdx.x * 32;
  const int hh = blockIdx.y, bb = blockIdx.z;
  const long qkbase = ((long)bb * SEQ) * HD + hh * DKDIM;          // elems
  const long vtbase = (long)(bb * NHEAD + hh) * DKDIM * SEQ;       // elems
  const int w = t >> 6;

  // ---- prologue: stage Q via global_load_lds (inverse-swizzled source) ----
  {
    const int row = t >> 3;
    const int cb = (t & 7) << 4;
    const int src = cb ^ ((row & 7) << 4);
    GLDS16(Qg + qkbase + (long)(q0 + row) * HD + (src >> 1), QS + w * 1024);
  }
  for (int i = t; i < NRELV * 64; i += 256) {
    EKs[i >> 6][i & 63] = ekg[i];
    EVs[i >> 6][i & 63] = evg[i];
  }
  for (int i = t; i < 32 * NRELV; i += 256) ((float*)WS)[i] = 0.f;
  if (t < 32) LROW[t] = 0.f;
  __syncthreads();

  // ---- qek[m][r] = Q[m,:] . ek[r,:] ----
  for (int o = t; o < 32 * NRELV; o += 256) {
    const int m = o & 31, r = o >> 5;
    float s = 0.f;
    for (int d = 0; d < 64; ++d)
      s += bf2f(*(const ushortT*)(QS + SWZ(m, d * 2))) * EKs[r][d];
    QEK[m][r] = s;
  }

  const int lane = t & 63;
  const int wr = w >> 1, wc = w & 1;
  const int l15 = lane & 15, lhi = lane >> 4;

  __syncthreads();
  short8 qa[2];
  qa[0] = *(const short8*)(QS + SWZ(wr * 16 + l15, lhi * 16));
  qa[1] = *(const short8*)(QS + SWZ(wr * 16 + l15, 64 + lhi * 16));

  f32x4 oacc[2] = {};

  for (int kt = 0; kt < 8; ++kt) {
    const int k0t = kt * 64;
    __syncthreads();                          // S1: prev PV done with KV/PS
    #pragma unroll
    for (int i = 0; i < 2; ++i) {
      const int tl = i * 256 + t;
      const int row = tl >> 3;
      const int cb = (tl & 7) << 4;
      const int src = cb ^ ((row & 7) << 4);
      GLDS16(Kg + qkbase + (long)(k0t + row) * HD + (src >> 1),
             KV + i * 4096 + w * 1024);
    }
    __syncthreads();                          // S2: K ready
    f32x4 sacc[2] = {};
    #pragma unroll
    for (int kk = 0; kk < 2; ++kk) {
      const short8 b0 = *(const short8*)(KV + SWZ(wc * 32 + l15,      kk * 64 + lhi * 16));
      const short8 b1 = *(const short8*)(KV + SWZ(wc * 32 + 16 + l15, kk * 64 + lhi * 16));
      sacc[0] = __builtin_amdgcn_mfma_f32_16x16x32_bf16(qa[kk], b0, sacc[0], 0, 0, 0);
      sacc[1] = __builtin_amdgcn_mfma_f32_16x16x32_bf16(qa[kk], b1, sacc[1], 0, 0, 0);
    }
    #pragma unroll
    for (int reg = 0; reg < 4; ++reg) {
      const int m = wr * 16 + lhi * 4 + reg;
      const int dbase = k0t + wc * 32 - (q0 + m);
      const bool uniHi = (dbase >= MREL + 1);
      const bool uniLo = (dbase + 31 <= -(MREL + 1));
      float rp = 0.f;
      #pragma unroll
      for (int nf = 0; nf < 2; ++nf) {
        const int keyl = wc * 32 + nf * 16 + l15;
        const int db = dbase + nf * 16 + l15;
        const float s = sacc[nf][reg] + QEK[m][relclamp(db)];
        const float p = __expf(s);
        *(ushortT*)(PS + SWZ(m, keyl * 2)) = f2bf(p);
        if (!uniHi && !uniLo) atomicAdd(&WS[m][relclamp(db)], p);
        rp += p;
      }
      rp += __shfl_xor(rp, 1); rp += __shfl_xor(rp, 2);
      rp += __shfl_xor(rp, 4); rp += __shfl_xor(rp, 8);
      if (l15 == 0) {
        atomicAdd(&LROW[m], rp);
        if (uniHi)      atomicAdd(&WS[m][2 * MREL], rp);
        else if (uniLo) atomicAdd(&WS[m][0], rp);
      }
    }
    __syncthreads();                          // S3: P ready; K reads done
    #pragma unroll
    for (int i = 0; i < 2; ++i) {
      const int tl = i * 256 + t;
      const int row = tl >> 3;                // d
      const int cb = (tl & 7) << 4;
      const int src = cb ^ ((row & 7) << 4);
      GLDS16(Vt + vtbase + (long)row * SEQ + k0t + (src >> 1),
             KV + i * 4096 + w * 1024);
    }
    __syncthreads();                          // S4: V^T ready
    #pragma unroll
    for (int kk = 0; kk < 2; ++kk) {
      const short8 pa = *(const short8*)(PS + SWZ(wr * 16 + l15, kk * 64 + lhi * 16));
      const short8 v0 = *(const short8*)(KV + SWZ(wc * 32 + l15,      kk * 64 + lhi * 16));
      const short8 v1 = *(const short8*)(KV + SWZ(wc * 32 + 16 + l15, kk * 64 + lhi * 16));
      oacc[0] = __builtin_amdgcn_mfma_f32_16x16x32_bf16(pa, v0, oacc[0], 0, 0, 0);
      oacc[1] = __builtin_amdgcn_mfma_f32_16x16x32_bf16(pa, v1, oacc[1], 0, 0, 0);
    }
  }

  // ---- epilogue: rel_v bucket matvec + normalize + write bf16 ----
  float rv0[4] = {}, rv1[4] = {};
  const int d0 = wc * 32 + l15, d1 = d0 + 16;
  for (int r = 0; r < NRELV; ++r) {
    const float e0 = EVs[r][d0], e1 = EVs[r][d1];
    #pragma unroll
    for (int reg = 0; reg < 4; ++reg) {
      const float wsr = WS[wr * 16 + lhi * 4 + reg][r];
      rv0[reg] += wsr * e0;
      rv1[reg] += wsr * e1;
    }
  }
  #pragma unroll
  for (int reg = 0; reg < 4; ++reg) {
    const int m = wr * 16 + lhi * 4 + reg;
    const float rinv = 1.f / LROW[m];
    Og[qkbase + (long)(q0 + m) * HD + d0] = f2bf((oacc[0][reg] + rv0[reg]) * rinv);
    Og[qkbase + (long)(q0 + m) * HD + d1] = f2bf((oacc[1][reg] + rv1[reg]) * rinv);
  }
}

extern "C" void kernel_launch(void* const* d_in, const int* in_sizes, int n_in,
                              void* d_out, int out_size, void* d_ws, size_t ws_size,
                              hipStream_t stream) {
  const float* x    = (const float*)d_in[0];
  const int*   mask = (const int*)d_in[1];
  const float* dw_w = (const float*)d_in[2];
  const float* dw_b = (const float*)d_in[3];
  const float* pw_w = (const float*)d_in[4];
  const float* pw_b = (const float*)d_in[5];
  const float* lncg = (const float*)d_in[6];
  const float* lncb = (const float*)d_in[7];
  const float* wq   = (const float*)d_in[8];
  const float* bq   = (const float*)d_in[9];
  const float* wk   = (const float*)d_in[10];
  const float* bk   = (const float*)d_in[11];
  const float* wv   = (const float*)d_in[12];
  const float* bv   = (const float*)d_in[13];
  const float* wo   = (const float*)d_in[14];
  const float* bo   = (const float*)d_in[15];
  const float* ek   = (const float*)d_in[16];
  const float* ev   = (const float*)d_in[17];
  const float* lnag = (const float*)d_in[18];
  const float* lnab = (const float*)d_in[19];
  const float* wff  = (const float*)d_in[20];
  const float* bff  = (const float*)d_in[21];
  const float* lnfg = (const float*)d_in[22];
  const float* lnfb = (const float*)d_in[23];

  float* out = (float*)d_out;
  float* PE   = (float*)d_ws;                      // SEQ*HD f32
  float* NB32 = PE + SEQ * HD;                     // TOK*HD f32 (LN out for dwconv)
  ushortT* ABF = (ushortT*)(NB32 + (long)TOK * HD);// TOK*HD bf16 (activations)
  ushortT* QBF = ABF + (long)TOK * HD;
  ushortT* KBF = QBF + (long)TOK * HD;
  ushortT* VTB = KBF + (long)TOK * HD;             // V^T bf16 [b,h,d][s]
  ushortT* WBF = VTB + (long)TOK * HD;             // 7 * HD*HD bf16 weights
  const long WSZ = (long)HD * HD;

  pe_kernel<<<SEQ * HD / 256, 256, 0, stream>>>(PE);
  addpos_kernel<<<TOK * HD / 256, 256, 0, stream>>>(x, mask, PE, out);
  convw_kernel<<<7 * HD * HD / 4 / 256, 256, 0, stream>>>(
      pw_w, pw_w + WSZ, wq, wk, wv, wo, wff, WBF);

  for (int i = 0; i < 2; ++i) {
    ln_kernel<false><<<TOK, 256, 0, stream>>>(out, lncg + i * HD, lncb + i * HD, NB32);
    dwconv_kernel<<<TOK * HD / 256, 256, 0, stream>>>(NB32, dw_w + i * HD * 7, dw_b + i * HD, ABF);
    mgemm_kernel<2><<<512, 256, 0, stream>>>(ABF, WBF + i * WSZ, pw_b + i * HD, out, nullptr);
  }

  ln_kernel<true><<<TOK, 256, 0, stream>>>(out, lnag, lnab, ABF);
  mgemm_kernel<3><<<512, 256, 0, stream>>>(ABF, WBF + 2 * WSZ, bq, nullptr, QBF);
  mgemm_kernel<3><<<512, 256, 0, stream>>>(ABF, WBF + 3 * WSZ, bk, nullptr, KBF);
  mgemm_kernel<4><<<512, 256, 0, stream>>>(ABF, WBF + 4 * WSZ, bv, nullptr, VTB);
  attn_kernel<<<dim3(SEQ / 32, NHEAD, BATCH), 256, 0, stream>>>(QBF, KBF, VTB, ek, ev, ABF);
  mgemm_kernel<1><<<512, 256, 0, stream>>>(ABF, WBF + 5 * WSZ, bo, out, nullptr);

  ln_kernel<true><<<TOK, 256, 0, stream>>>(out, lnfg, lnfb, ABF);
  mgemm_kernel<2><<<512, 256, 0, stream>>>(ABF, WBF + 6 * WSZ, bff, out, nullptr);
}

// Round 4
// 416.707 us; speedup vs baseline: 6.4558x; 1.2227x over previous
//
#include <hip/hip_runtime.h>

#define SEQ 512
#define HD 512
#define BATCH 32
#define TOK (BATCH * SEQ)   // 16384
#define NHEAD 8
#define DKDIM 64
#define MREL 16
#define NRELV 33

using short8 = __attribute__((ext_vector_type(8))) short;
using f32x4  = __attribute__((ext_vector_type(4))) float;
typedef unsigned short ushortT;

#define AS1 __attribute__((address_space(1)))
#define AS3 __attribute__((address_space(3)))
#define GLDS16(g, l) __builtin_amdgcn_global_load_lds( \
    (const AS1 unsigned int*)(const void*)(g), \
    (AS3 unsigned int*)(void*)(l), 16, 0, 0)

__device__ __forceinline__ ushortT f2bf(float x) {
  union { float f; unsigned u; } c; c.f = x;
  unsigned r = c.u + 0x7FFF + ((c.u >> 16) & 1);
  return (ushortT)(r >> 16);
}

__device__ __forceinline__ float bf2f(ushortT h) {
  union { unsigned u; float f; } c; c.u = (unsigned)h << 16;
  return c.f;
}

// ---------------- positional-encoding table (S x H) ----------------
__global__ __launch_bounds__(256) void pe_kernel(float* __restrict__ PE) {
  const int i = blockIdx.x * 256 + threadIdx.x;   // < SEQ*HD
  const int s = i >> 9, h = i & (HD - 1);
  float v = 0.f;
  if (s > 0) {
    const int i2 = h & ~1;
    const float div = expf((float)i2 * (-9.210340371976184f / (float)HD)); // ln(10000)
    const float ang = (float)(s - 1) * div;
    v = (h & 1) ? cosf(ang) : sinf(ang);
  }
  PE[i] = v;
}

// ---------------- x = x + pe * mask ----------------
__global__ __launch_bounds__(256) void addpos_kernel(
    const float* __restrict__ x, const int* __restrict__ mask,
    const float* __restrict__ PE, float* __restrict__ out) {
  const long i = (long)blockIdx.x * 256 + threadIdx.x;   // < TOK*HD
  const int h = (int)(i & (HD - 1));
  const long bs = i >> 9;
  const int s = (int)(bs & (SEQ - 1));
  out[i] = x[i] + PE[s * HD + h] * (float)mask[bs];
}

// ---------------- weights f32 -> bf16 (7 matrices of HD*HD) ----------------
__global__ __launch_bounds__(256) void convw_kernel(
    const float* __restrict__ s0, const float* __restrict__ s1,
    const float* __restrict__ s2, const float* __restrict__ s3,
    const float* __restrict__ s4, const float* __restrict__ s5,
    const float* __restrict__ s6, ushortT* __restrict__ dst) {
  const int i = blockIdx.x * 256 + threadIdx.x;     // < 7 * HD*HD/4
  const int region = i >> 16;                        // HD*HD/4 = 65536
  const int off = i & 65535;
  const float* s = region == 0 ? s0 : region == 1 ? s1 : region == 2 ? s2 :
                   region == 3 ? s3 : region == 4 ? s4 : region == 5 ? s5 : s6;
  const float4 v = ((const float4*)s)[off];
  ushort4 o;
  o.x = f2bf(v.x); o.y = f2bf(v.y); o.z = f2bf(v.z); o.w = f2bf(v.w);
  *(ushort4*)&dst[(long)i * 4] = o;
}

// ---------------- LayerNorm, one block per row; BF: bf16 out ----------------
template <bool BF>
__global__ __launch_bounds__(256) void ln_kernel(
    const float* __restrict__ X, const float* __restrict__ g,
    const float* __restrict__ bta, void* __restrict__ Yv) {
  const int row = blockIdx.x;
  const int t = threadIdx.x;
  const float* xr = X + (long)row * HD;
  const float x0 = xr[t], x1 = xr[t + 256];
  float s = x0 + x1, q = x0 * x0 + x1 * x1;
  #pragma unroll
  for (int off = 32; off > 0; off >>= 1) {
    s += __shfl_down(s, off);
    q += __shfl_down(q, off);
  }
  __shared__ float sh[10];
  const int w = t >> 6;
  if ((t & 63) == 0) { sh[w] = s; sh[4 + w] = q; }
  __syncthreads();
  if (t == 0) {
    const float S_ = sh[0] + sh[1] + sh[2] + sh[3];
    const float Q_ = sh[4] + sh[5] + sh[6] + sh[7];
    const float mu = S_ * (1.f / (float)HD);
    const float var = Q_ * (1.f / (float)HD) - mu * mu;
    sh[8] = mu;
    sh[9] = rsqrtf(var + 1e-5f);
  }
  __syncthreads();
  const float mu = sh[8], rstd = sh[9];
  const float y0 = (x0 - mu) * rstd * g[t] + bta[t];
  const float y1 = (x1 - mu) * rstd * g[t + 256] + bta[t + 256];
  if (BF) {
    ushortT* yr = (ushortT*)Yv + (long)row * HD;
    yr[t] = f2bf(y0);
    yr[t + 256] = f2bf(y1);
  } else {
    float* yr = (float*)Yv + (long)row * HD;
    yr[t] = y0;
    yr[t + 256] = y1;
  }
}

// ---------------- depthwise conv1d K=7, pad 3, bf16 out ----------------
__global__ __launch_bounds__(256) void dwconv_kernel(
    const float* __restrict__ N_, const float* __restrict__ w,
    const float* __restrict__ bias, ushortT* __restrict__ Hout) {
  const long i = (long)blockIdx.x * 256 + threadIdx.x;   // < TOK*HD
  const int cch = (int)(i & (HD - 1));
  const long bs = i >> 9;
  const int s = (int)(bs & (SEQ - 1));
  const long rowb = bs - s;                               // b*SEQ
  float acc = bias[cch];
  #pragma unroll
  for (int k = 0; k < 7; ++k) {
    const int ss = s + k - 3;
    if (ss >= 0 && ss < SEQ)
      acc += N_[(rowb + ss) * HD + cch] * w[cch * 7 + k];
  }
  Hout[i] = f2bf(acc);
}

// ---------------- bf16 MFMA GEMM: G[r,c] = A[r,:] . W[c,:] + bias[c] ----------
// 128x128 tile, BK=32, 4 waves (2x2), global_load_lds staging.
// MODE 0: C=G  1: C+=G  2: C+=relu(G)  3: Cb=bf16(G)  4: Cb=V^T bf16(G)
template <int MODE>
__global__ __launch_bounds__(256) void mgemm_kernel(
    const ushortT* __restrict__ A, const ushortT* __restrict__ W,
    const float* __restrict__ bias, float* __restrict__ C,
    ushortT* __restrict__ Cb) {
  __shared__ ushortT Als[128 * 32];
  __shared__ ushortT Bls[128 * 32];
  const int t = threadIdx.x;
  const int bid = blockIdx.x;                    // 512 blocks
  const int m_blk = (bid & 7) * 16 + ((bid >> 3) & 15);  // XCD-chunked
  const int n_blk = bid >> 7;
  const int row0 = m_blk * 128;
  const int col0 = n_blk * 128;
  const int lane = t & 63, w = t >> 6;
  const int wr = w >> 1, wc = w & 1;
  const int l15 = lane & 15, lhi = lane >> 4;

  f32x4 acc[4][4] = {};

  for (int kt = 0; kt < 16; ++kt) {
    __syncthreads();
    #pragma unroll
    for (int i = 0; i < 2; ++i) {
      const int tl = i * 256 + t;
      const int r = tl >> 2, ch = tl & 3;        // row, 16B chunk
      GLDS16(A + (long)(row0 + r) * HD + kt * 32 + ch * 8,
             Als + (i * 256 + w * 64) * 8);
      GLDS16(W + (long)(col0 + r) * HD + kt * 32 + ch * 8,
             Bls + (i * 256 + w * 64) * 8);
    }
    __syncthreads();
    short8 af[4], bf[4];
    #pragma unroll
    for (int i = 0; i < 4; ++i) {
      af[i] = *(const short8*)&Als[(wr * 64 + i * 16 + l15) * 32 + lhi * 8];
      bf[i] = *(const short8*)&Bls[(wc * 64 + i * 16 + l15) * 32 + lhi * 8];
    }
    #pragma unroll
    for (int mi = 0; mi < 4; ++mi)
      #pragma unroll
      for (int ni = 0; ni < 4; ++ni)
        acc[mi][ni] = __builtin_amdgcn_mfma_f32_16x16x32_bf16(af[mi], bf[ni], acc[mi][ni], 0, 0, 0);
  }

  #pragma unroll
  for (int ni = 0; ni < 4; ++ni) {
    const int c = col0 + wc * 64 + ni * 16 + l15;
    const float bz = bias[c];
    #pragma unroll
    for (int mi = 0; mi < 4; ++mi) {
      if (MODE == 4) {
        const int tok0 = row0 + wr * 64 + mi * 16 + lhi * 4;
        const int b = tok0 >> 9, s = tok0 & (SEQ - 1);
        const int h = c >> 6, d = c & 63;
        ushort4 pk;
        pk.x = f2bf(acc[mi][ni][0] + bz);
        pk.y = f2bf(acc[mi][ni][1] + bz);
        pk.z = f2bf(acc[mi][ni][2] + bz);
        pk.w = f2bf(acc[mi][ni][3] + bz);
        *(ushort4*)&Cb[((long)((b * NHEAD + h) * DKDIM + d) << 9) + s] = pk;
      } else {
        #pragma unroll
        for (int reg = 0; reg < 4; ++reg) {
          const int rrow = row0 + wr * 64 + mi * 16 + lhi * 4 + reg;
          const float g = acc[mi][ni][reg] + bz;
          const long idx = (long)rrow * HD + c;
          if (MODE == 0)      C[idx] = g;
          else if (MODE == 1) C[idx] += g;
          else if (MODE == 2) C[idx] += fmaxf(g, 0.f);
          else                Cb[idx] = f2bf(g);
        }
      }
    }
  }
}

// ---------------- barrier-free MFMA attention with relative positions --------
// Grid (NHEAD, SEQ/256, BATCH), 512 threads = 8 waves. Each wave owns 32
// q-rows and sweeps all 512 keys independently (no __syncthreads in loop).
// K/V/Q fragments read directly from global (L2-resident slices).
// Shaw rel-k via qek table (12 MFMAs); rel-v via register bucket sums +
// single-writer wsmid LDS; bucket0 derived as rsum - hi - sum(mid).
__global__ __launch_bounds__(512, 4) void attn_kernel(
    const ushortT* __restrict__ Qg, const ushortT* __restrict__ Kg,
    const ushortT* __restrict__ Vt, const float* __restrict__ ekg,
    const float* __restrict__ evg, ushortT* __restrict__ Og) {
  __shared__ float EVs[NRELV][64];            // 8448 B
  __shared__ ushortT qekL[256 * 34];          // bf16, block-local q rows
  __shared__ ushortT wsmidL[8][32][32];       // [wave][row][db+15], db in (-16,16)
  __shared__ ushortT PSL[8 * 1024];           // per-wave P bounce, 2KB each

  const int t = threadIdx.x;
  const int lane = t & 63, w = t >> 6;
  const int l15 = lane & 15, lhi = lane >> 4;
  const int hh = blockIdx.x, qb = blockIdx.y, bb = blockIdx.z;
  const int q0w = qb * 256 + w * 32;          // wave's first global q row
  const long qkb = ((long)bb * SEQ) * HD + hh * DKDIM;
  const long vtb = (long)(bb * NHEAD + hh) * DKDIM * SEQ;

  // ---- prologue: stage EVs (block-shared), zero own wsmid ----
  for (int i = t; i < NRELV * 64; i += 512) ((float*)EVs)[i] = evg[i];
  {
    unsigned* wz = (unsigned*)&wsmidL[w][0][0];
    #pragma unroll
    for (int i = 0; i < 8; ++i) wz[lane + i * 64] = 0u;
  }
  __syncthreads();

  // ---- Q A-fragments (persistent) ----
  short8 qa[2][2];
  #pragma unroll
  for (int mfr = 0; mfr < 2; ++mfr)
    #pragma unroll
    for (int kk = 0; kk < 2; ++kk)
      qa[mfr][kk] = *(const short8*)&Qg[qkb + (long)(q0w + mfr * 16 + l15) * HD + kk * 32 + lhi * 8];

  // ---- qek via MFMA: qek[q][r] = Q[q,:].ek[r,:], r = nf*16+l15 ----
  {
    f32x4 qacc[2][3] = {};
    #pragma unroll
    for (int nf = 0; nf < 3; ++nf) {
      const int r = nf * 16 + l15;
      #pragma unroll
      for (int kk = 0; kk < 2; ++kk) {
        short8 ef;
        #pragma unroll
        for (int j = 0; j < 8; ++j)
          ef[j] = (short)(r < NRELV ? f2bf(ekg[r * 64 + kk * 32 + lhi * 8 + j]) : (ushortT)0);
        #pragma unroll
        for (int mfr = 0; mfr < 2; ++mfr)
          qacc[mfr][nf] = __builtin_amdgcn_mfma_f32_16x16x32_bf16(qa[mfr][kk], ef, qacc[mfr][nf], 0, 0, 0);
      }
    }
    #pragma unroll
    for (int mfr = 0; mfr < 2; ++mfr)
      #pragma unroll
      for (int nf = 0; nf < 3; ++nf) {
        const int r = nf * 16 + l15;
        if (r < NRELV) {
          #pragma unroll
          for (int reg = 0; reg < 4; ++reg)
            qekL[(w * 32 + mfr * 16 + lhi * 4 + reg) * 34 + r] = f2bf(qacc[mfr][nf][reg]);
        }
      }
  }

  // ---- main loop over 16 key-tiles of 32, no barriers ----
  f32x4 oacc[2][4] = {};
  float rsum[2][4] = {}, wsHi[2][4] = {};
  char* psw = (char*)PSL + w * 2048;

  for (int kt = 0; kt < 16; ++kt) {
    const int k0 = kt * 32;
    // K fragments (B-operand): col=key, k=d
    short8 kf[2][2];
    #pragma unroll
    for (int nf = 0; nf < 2; ++nf)
      #pragma unroll
      for (int kk = 0; kk < 2; ++kk)
        kf[nf][kk] = *(const short8*)&Kg[qkb + (long)(k0 + nf * 16 + l15) * HD + kk * 32 + lhi * 8];
    // S = Q K^T
    f32x4 sacc[2][2] = {};
    #pragma unroll
    for (int mfr = 0; mfr < 2; ++mfr)
      #pragma unroll
      for (int nf = 0; nf < 2; ++nf)
        #pragma unroll
        for (int kk = 0; kk < 2; ++kk)
          sacc[mfr][nf] = __builtin_amdgcn_mfma_f32_16x16x32_bf16(qa[mfr][kk], kf[nf][kk], sacc[mfr][nf], 0, 0, 0);
    // V fragments for PV (B-operand): col=d, k=key
    short8 vf[4];
    #pragma unroll
    for (int nd = 0; nd < 4; ++nd)
      vf[nd] = *(const short8*)&Vt[vtb + (long)(nd * 16 + l15) * SEQ + k0 + lhi * 8];
    // exp path: p = exp(S + qek), buckets, P -> LDS bounce
    #pragma unroll
    for (int mfr = 0; mfr < 2; ++mfr) {
      #pragma unroll
      for (int reg = 0; reg < 4; ++reg) {
        const int row = mfr * 16 + lhi * 4 + reg;   // wave-local
        const int qg = q0w + row;                   // global q
        #pragma unroll
        for (int nf = 0; nf < 2; ++nf) {
          const int key = k0 + nf * 16 + l15;
          const int db = key - qg;
          const int rcl = min(max(db, -MREL), MREL) + MREL;
          const float sval = sacc[mfr][nf][reg] + bf2f(qekL[(w * 32 + row) * 34 + rcl]);
          const float p = __expf(sval);
          const int byte = (nf * 16 + l15) * 2;
          *(ushortT*)(psw + row * 64 + (byte ^ (((row >> 2) & 3) << 4))) = f2bf(p);
          rsum[mfr][reg] += p;
          if (db >= MREL)       wsHi[mfr][reg] += p;
          else if (db > -MREL)  wsmidL[w][row][db + MREL - 1] = f2bf(p);
        }
      }
    }
    // PV: O += P . V^T  (A = P rows=q from bounce, B = V cols=d)
    #pragma unroll
    for (int mfr = 0; mfr < 2; ++mfr) {
      const int row = mfr * 16 + l15;
      const short8 pa = *(const short8*)(psw + row * 64 + ((lhi * 16) ^ (((row >> 2) & 3) << 4)));
      #pragma unroll
      for (int nd = 0; nd < 4; ++nd)
        oacc[mfr][nd] = __builtin_amdgcn_mfma_f32_16x16x32_bf16(pa, vf[nd], oacc[mfr][nd], 0, 0, 0);
    }
  }

  // ---- epilogue: reduce row sums across l15, rel_v matvec, normalize ----
  #pragma unroll
  for (int mfr = 0; mfr < 2; ++mfr)
    #pragma unroll
    for (int reg = 0; reg < 4; ++reg) {
      float rs = rsum[mfr][reg], hi = wsHi[mfr][reg];
      #pragma unroll
      for (int m = 1; m <= 8; m <<= 1) {
        rs += __shfl_xor(rs, m);
        hi += __shfl_xor(hi, m);
      }
      rsum[mfr][reg] = rs;
      wsHi[mfr][reg] = hi;
    }

  float midsum[2][4] = {};
  for (int i = 1; i <= 31; ++i) {            // middle buckets r = 1..31
    float e[4];
    #pragma unroll
    for (int nd = 0; nd < 4; ++nd) e[nd] = EVs[i][nd * 16 + l15];
    #pragma unroll
    for (int mfr = 0; mfr < 2; ++mfr)
      #pragma unroll
      for (int reg = 0; reg < 4; ++reg) {
        const int row = mfr * 16 + lhi * 4 + reg;
        const float m = bf2f(wsmidL[w][row][i - 1]);
        midsum[mfr][reg] += m;
        #pragma unroll
        for (int nd = 0; nd < 4; ++nd) oacc[mfr][nd][reg] += m * e[nd];
      }
  }
  {
    float el[4], eh[4];
    #pragma unroll
    for (int nd = 0; nd < 4; ++nd) {
      el[nd] = EVs[0][nd * 16 + l15];
      eh[nd] = EVs[NRELV - 1][nd * 16 + l15];
    }
    #pragma unroll
    for (int mfr = 0; mfr < 2; ++mfr)
      #pragma unroll
      for (int reg = 0; reg < 4; ++reg) {
        const float hi = wsHi[mfr][reg];
        const float lo = rsum[mfr][reg] - hi - midsum[mfr][reg];
        #pragma unroll
        for (int nd = 0; nd < 4; ++nd)
          oacc[mfr][nd][reg] += hi * eh[nd] + lo * el[nd];
      }
  }
  #pragma unroll
  for (int mfr = 0; mfr < 2; ++mfr)
    #pragma unroll
    for (int reg = 0; reg < 4; ++reg) {
      const int qg = q0w + mfr * 16 + lhi * 4 + reg;
      const float rinv = 1.f / rsum[mfr][reg];
      #pragma unroll
      for (int nd = 0; nd < 4; ++nd)
        Og[qkb + (long)qg * HD + nd * 16 + l15] = f2bf(oacc[mfr][nd][reg] * rinv);
    }
}

extern "C" void kernel_launch(void* const* d_in, const int* in_sizes, int n_in,
                              void* d_out, int out_size, void* d_ws, size_t ws_size,
                              hipStream_t stream) {
  const float* x    = (const float*)d_in[0];
  const int*   mask = (const int*)d_in[1];
  const float* dw_w = (const float*)d_in[2];
  const float* dw_b = (const float*)d_in[3];
  const float* pw_w = (const float*)d_in[4];
  const float* pw_b = (const float*)d_in[5];
  const float* lncg = (const float*)d_in[6];
  const float* lncb = (const float*)d_in[7];
  const float* wq   = (const float*)d_in[8];
  const float* bq   = (const float*)d_in[9];
  const float* wk   = (const float*)d_in[10];
  const float* bk   = (const float*)d_in[11];
  const float* wv   = (const float*)d_in[12];
  const float* bv   = (const float*)d_in[13];
  const float* wo   = (const float*)d_in[14];
  const float* bo   = (const float*)d_in[15];
  const float* ek   = (const float*)d_in[16];
  const float* ev   = (const float*)d_in[17];
  const float* lnag = (const float*)d_in[18];
  const float* lnab = (const float*)d_in[19];
  const float* wff  = (const float*)d_in[20];
  const float* bff  = (const float*)d_in[21];
  const float* lnfg = (const float*)d_in[22];
  const float* lnfb = (const float*)d_in[23];

  float* out = (float*)d_out;
  float* PE   = (float*)d_ws;                      // SEQ*HD f32
  float* NB32 = PE + SEQ * HD;                     // TOK*HD f32 (LN out for dwconv)
  ushortT* ABF = (ushortT*)(NB32 + (long)TOK * HD);// TOK*HD bf16 (activations)
  ushortT* QBF = ABF + (long)TOK * HD;
  ushortT* KBF = QBF + (long)TOK * HD;
  ushortT* VTB = KBF + (long)TOK * HD;             // V^T bf16 [b,h,d][s]
  ushortT* WBF = VTB + (long)TOK * HD;             // 7 * HD*HD bf16 weights
  const long WSZ = (long)HD * HD;

  pe_kernel<<<SEQ * HD / 256, 256, 0, stream>>>(PE);
  addpos_kernel<<<TOK * HD / 256, 256, 0, stream>>>(x, mask, PE, out);
  convw_kernel<<<7 * HD * HD / 4 / 256, 256, 0, stream>>>(
      pw_w, pw_w + WSZ, wq, wk, wv, wo, wff, WBF);

  for (int i = 0; i < 2; ++i) {
    ln_kernel<false><<<TOK, 256, 0, stream>>>(out, lncg + i * HD, lncb + i * HD, NB32);
    dwconv_kernel<<<TOK * HD / 256, 256, 0, stream>>>(NB32, dw_w + i * HD * 7, dw_b + i * HD, ABF);
    mgemm_kernel<2><<<512, 256, 0, stream>>>(ABF, WBF + i * WSZ, pw_b + i * HD, out, nullptr);
  }

  ln_kernel<true><<<TOK, 256, 0, stream>>>(out, lnag, lnab, ABF);
  mgemm_kernel<3><<<512, 256, 0, stream>>>(ABF, WBF + 2 * WSZ, bq, nullptr, QBF);
  mgemm_kernel<3><<<512, 256, 0, stream>>>(ABF, WBF + 3 * WSZ, bk, nullptr, KBF);
  mgemm_kernel<4><<<512, 256, 0, stream>>>(ABF, WBF + 4 * WSZ, bv, nullptr, VTB);
  attn_kernel<<<dim3(NHEAD, SEQ / 256, BATCH), 512, 0, stream>>>(QBF, KBF, VTB, ek, ev, ABF);
  mgemm_kernel<1><<<512, 256, 0, stream>>>(ABF, WBF + 5 * WSZ, bo, out, nullptr);

  ln_kernel<true><<<TOK, 256, 0, stream>>>(out, lnfg, lnfb, ABF);
  mgemm_kernel<2><<<512, 256, 0, stream>>>(ABF, WBF + 6 * WSZ, bff, out, nullptr);
}

// Round 5
// 397.817 us; speedup vs baseline: 6.7623x; 1.0475x over previous
//
#include <hip/hip_runtime.h>

#define SEQ 512
#define HD 512
#define BATCH 32
#define TOK (BATCH * SEQ)   // 16384
#define NHEAD 8
#define DKDIM 64
#define MREL 16
#define NRELV 33

using short8 = __attribute__((ext_vector_type(8))) short;
using f32x4  = __attribute__((ext_vector_type(4))) float;
using f32x16 = __attribute__((ext_vector_type(16))) float;
typedef unsigned short ushortT;

#define AS1 __attribute__((address_space(1)))
#define AS3 __attribute__((address_space(3)))
#define GLDS16(g, l) __builtin_amdgcn_global_load_lds( \
    (const AS1 unsigned int*)(const void*)(g), \
    (AS3 unsigned int*)(void*)(l), 16, 0, 0)

__device__ __forceinline__ ushortT f2bf(float x) {
  union { float f; unsigned u; } c; c.f = x;
  unsigned r = c.u + 0x7FFF + ((c.u >> 16) & 1);
  return (ushortT)(r >> 16);
}

__device__ __forceinline__ float bf2f(ushortT h) {
  union { unsigned u; float f; } c; c.u = (unsigned)h << 16;
  return c.f;
}

// ---------------- positional-encoding table (S x H) ----------------
__global__ __launch_bounds__(256) void pe_kernel(float* __restrict__ PE) {
  const int i = blockIdx.x * 256 + threadIdx.x;   // < SEQ*HD
  const int s = i >> 9, h = i & (HD - 1);
  float v = 0.f;
  if (s > 0) {
    const int i2 = h & ~1;
    const float div = expf((float)i2 * (-9.210340371976184f / (float)HD)); // ln(10000)
    const float ang = (float)(s - 1) * div;
    v = (h & 1) ? cosf(ang) : sinf(ang);
  }
  PE[i] = v;
}

// ---------------- x = x + pe * mask ----------------
__global__ __launch_bounds__(256) void addpos_kernel(
    const float* __restrict__ x, const int* __restrict__ mask,
    const float* __restrict__ PE, float* __restrict__ out) {
  const long i = (long)blockIdx.x * 256 + threadIdx.x;   // < TOK*HD
  const int h = (int)(i & (HD - 1));
  const long bs = i >> 9;
  const int s = (int)(bs & (SEQ - 1));
  out[i] = x[i] + PE[s * HD + h] * (float)mask[bs];
}

// ---------------- weights f32 -> bf16 (7 matrices of HD*HD) ----------------
__global__ __launch_bounds__(256) void convw_kernel(
    const float* __restrict__ s0, const float* __restrict__ s1,
    const float* __restrict__ s2, const float* __restrict__ s3,
    const float* __restrict__ s4, const float* __restrict__ s5,
    const float* __restrict__ s6, ushortT* __restrict__ dst) {
  const int i = blockIdx.x * 256 + threadIdx.x;     // < 7 * HD*HD/4
  const int region = i >> 16;                        // HD*HD/4 = 65536
  const int off = i & 65535;
  const float* s = region == 0 ? s0 : region == 1 ? s1 : region == 2 ? s2 :
                   region == 3 ? s3 : region == 4 ? s4 : region == 5 ? s5 : s6;
  const float4 v = ((const float4*)s)[off];
  ushort4 o;
  o.x = f2bf(v.x); o.y = f2bf(v.y); o.z = f2bf(v.z); o.w = f2bf(v.w);
  *(ushort4*)&dst[(long)i * 4] = o;
}

// ---------------- LayerNorm, one block per row; BF: bf16 out ----------------
template <bool BF>
__global__ __launch_bounds__(256) void ln_kernel(
    const float* __restrict__ X, const float* __restrict__ g,
    const float* __restrict__ bta, void* __restrict__ Yv) {
  const int row = blockIdx.x;
  const int t = threadIdx.x;
  const float* xr = X + (long)row * HD;
  const float x0 = xr[t], x1 = xr[t + 256];
  float s = x0 + x1, q = x0 * x0 + x1 * x1;
  #pragma unroll
  for (int off = 32; off > 0; off >>= 1) {
    s += __shfl_down(s, off);
    q += __shfl_down(q, off);
  }
  __shared__ float sh[10];
  const int w = t >> 6;
  if ((t & 63) == 0) { sh[w] = s; sh[4 + w] = q; }
  __syncthreads();
  if (t == 0) {
    const float S_ = sh[0] + sh[1] + sh[2] + sh[3];
    const float Q_ = sh[4] + sh[5] + sh[6] + sh[7];
    const float mu = S_ * (1.f / (float)HD);
    const float var = Q_ * (1.f / (float)HD) - mu * mu;
    sh[8] = mu;
    sh[9] = rsqrtf(var + 1e-5f);
  }
  __syncthreads();
  const float mu = sh[8], rstd = sh[9];
  const float y0 = (x0 - mu) * rstd * g[t] + bta[t];
  const float y1 = (x1 - mu) * rstd * g[t + 256] + bta[t + 256];
  if (BF) {
    ushortT* yr = (ushortT*)Yv + (long)row * HD;
    yr[t] = f2bf(y0);
    yr[t + 256] = f2bf(y1);
  } else {
    float* yr = (float*)Yv + (long)row * HD;
    yr[t] = y0;
    yr[t + 256] = y1;
  }
}

// ---------------- depthwise conv1d K=7, pad 3, bf16 in/out ----------------
__global__ __launch_bounds__(256) void dwconv_kernel(
    const ushortT* __restrict__ N_, const float* __restrict__ w,
    const float* __restrict__ bias, ushortT* __restrict__ Hout) {
  const long i = (long)blockIdx.x * 256 + threadIdx.x;   // < TOK*HD
  const int cch = (int)(i & (HD - 1));
  const long bs = i >> 9;
  const int s = (int)(bs & (SEQ - 1));
  const long rowb = bs - s;                               // b*SEQ
  float acc = bias[cch];
  #pragma unroll
  for (int k = 0; k < 7; ++k) {
    const int ss = s + k - 3;
    if (ss >= 0 && ss < SEQ)
      acc += bf2f(N_[(rowb + ss) * HD + cch]) * w[cch * 7 + k];
  }
  Hout[i] = f2bf(acc);
}

// ---------------- bf16 MFMA GEMM: G[r,c] = A[r,:] . W[c,:] + bias[c] ----------
// 128x128 tile, BK=32, 4 waves (2x2), global_load_lds staging.
// MODE 0: C=G  1: C+=G  2: C+=relu(G)  3: Cb=bf16(G)  4: Cb=V^T bf16(G)
template <int MODE>
__global__ __launch_bounds__(256) void mgemm_kernel(
    const ushortT* __restrict__ A, const ushortT* __restrict__ W,
    const float* __restrict__ bias, float* __restrict__ C,
    ushortT* __restrict__ Cb) {
  __shared__ ushortT Als[128 * 32];
  __shared__ ushortT Bls[128 * 32];
  const int t = threadIdx.x;
  const int bid = blockIdx.x;                    // 512 blocks
  const int m_blk = (bid & 7) * 16 + ((bid >> 3) & 15);  // XCD-chunked
  const int n_blk = bid >> 7;
  const int row0 = m_blk * 128;
  const int col0 = n_blk * 128;
  const int lane = t & 63, w = t >> 6;
  const int wr = w >> 1, wc = w & 1;
  const int l15 = lane & 15, lhi = lane >> 4;

  f32x4 acc[4][4] = {};

  for (int kt = 0; kt < 16; ++kt) {
    __syncthreads();
    #pragma unroll
    for (int i = 0; i < 2; ++i) {
      const int tl = i * 256 + t;
      const int r = tl >> 2, ch = tl & 3;        // row, 16B chunk
      GLDS16(A + (long)(row0 + r) * HD + kt * 32 + ch * 8,
             Als + (i * 256 + w * 64) * 8);
      GLDS16(W + (long)(col0 + r) * HD + kt * 32 + ch * 8,
             Bls + (i * 256 + w * 64) * 8);
    }
    __syncthreads();
    short8 af[4], bf[4];
    #pragma unroll
    for (int i = 0; i < 4; ++i) {
      af[i] = *(const short8*)&Als[(wr * 64 + i * 16 + l15) * 32 + lhi * 8];
      bf[i] = *(const short8*)&Bls[(wc * 64 + i * 16 + l15) * 32 + lhi * 8];
    }
    #pragma unroll
    for (int mi = 0; mi < 4; ++mi)
      #pragma unroll
      for (int ni = 0; ni < 4; ++ni)
        acc[mi][ni] = __builtin_amdgcn_mfma_f32_16x16x32_bf16(af[mi], bf[ni], acc[mi][ni], 0, 0, 0);
  }

  #pragma unroll
  for (int ni = 0; ni < 4; ++ni) {
    const int c = col0 + wc * 64 + ni * 16 + l15;
    const float bz = bias[c];
    #pragma unroll
    for (int mi = 0; mi < 4; ++mi) {
      if (MODE == 4) {
        const int tok0 = row0 + wr * 64 + mi * 16 + lhi * 4;
        const int b = tok0 >> 9, s = tok0 & (SEQ - 1);
        const int h = c >> 6, d = c & 63;
        ushort4 pk;
        pk.x = f2bf(acc[mi][ni][0] + bz);
        pk.y = f2bf(acc[mi][ni][1] + bz);
        pk.z = f2bf(acc[mi][ni][2] + bz);
        pk.w = f2bf(acc[mi][ni][3] + bz);
        *(ushort4*)&Cb[((long)((b * NHEAD + h) * DKDIM + d) << 9) + s] = pk;
      } else {
        #pragma unroll
        for (int reg = 0; reg < 4; ++reg) {
          const int rrow = row0 + wr * 64 + mi * 16 + lhi * 4 + reg;
          const float g = acc[mi][ni][reg] + bz;
          const long idx = (long)rrow * HD + c;
          if (MODE == 0)      C[idx] = g;
          else if (MODE == 1) C[idx] += g;
          else if (MODE == 2) C[idx] += fmaxf(g, 0.f);
          else                Cb[idx] = f2bf(g);
        }
      }
    }
  }
}

// ---------------- swapped-QK 32x32 MFMA attention, no LDS P-bounce ----------
// Grid (NHEAD, SEQ/256, BATCH), 512 threads = 8 waves; wave owns 32 q rows.
// sacc = mfma(K,Q): lane holds P column (q = lane&31, 16 keys in regs).
// P -> PV A-frag via bf16 packs + v_permlane32_swap_b32 (register-only).
// Tile-class specialization: hi/lo-uniform tiles skip clamp/LDS entirely.
__global__ __launch_bounds__(512, 4) void attn_kernel(
    const ushortT* __restrict__ Qg, const ushortT* __restrict__ Kg,
    const ushortT* __restrict__ Vt, const float* __restrict__ ekg,
    const float* __restrict__ evg, ushortT* __restrict__ Og) {
  __shared__ float EVs[NRELV][64];            // 8448 B
  __shared__ ushortT qekL[8][32][34];         // 17408 B  [wave][q][bucket]
  __shared__ ushortT wsmid[8][32][40];        // 20480 B  [wave][q][db+15]
  __shared__ float LROWw[8][32];              // 1024 B
  __shared__ float WHIw[8][32];               // 1024 B

  const int t = threadIdx.x;
  const int lane = t & 63, w = t >> 6;
  const int l31 = lane & 31, h = lane >> 5;
  const int hh = blockIdx.x, qb = blockIdx.y, bb = blockIdx.z;
  const int q0w = qb * 256 + w * 32;          // wave's first q row
  const long qkb = ((long)bb * SEQ) * HD + hh * DKDIM;
  const long vtb = (long)(bb * NHEAD + hh) * DKDIM * SEQ;

  // ---- prologue ----
  for (int i = t; i < NRELV * 64; i += 512) ((float*)EVs)[i] = evg[i];
  {
    unsigned* wz = (unsigned*)&wsmid[w][0][0];
    #pragma unroll
    for (int i = 0; i < 10; ++i) wz[lane + i * 64] = 0u;
  }
  __syncthreads();

  // Q B-fragments (col=q=l31, k=d): persistent
  short8 qB[4];
  #pragma unroll
  for (int kk = 0; kk < 4; ++kk)
    qB[kk] = *(const short8*)&Qg[qkb + (long)(q0w + l31) * HD + kk * 16 + h * 8];

  // qek[q][r] for r=0..31 via 4 MFMAs: A=ek rows=bucket, B=Q cols=q
  {
    f32x16 qacc = {};
    #pragma unroll
    for (int kk = 0; kk < 4; ++kk) {
      short8 ef;
      #pragma unroll
      for (int j = 0; j < 8; ++j)
        ef[j] = (short)f2bf(ekg[l31 * 64 + kk * 16 + h * 8 + j]);
      qacc = __builtin_amdgcn_mfma_f32_32x32x16_bf16(ef, qB[kk], qacc, 0, 0, 0);
    }
    #pragma unroll
    for (int r = 0; r < 16; ++r) {
      const int rr = (r & 3) + 8 * (r >> 2) + 4 * h;   // bucket row
      qekL[w][l31][rr] = f2bf(qacc[r]);
    }
  }
  // qekHi (bucket 32) / qekLo (bucket 0) as per-lane registers
  float qekHiR = 0.f, qekLoR = 0.f;
  #pragma unroll
  for (int kk = 0; kk < 4; ++kk)
    #pragma unroll
    for (int j = 0; j < 8; ++j) {
      const float qv = bf2f((ushortT)qB[kk][j]);
      const int d = kk * 16 + h * 8 + j;
      qekHiR += qv * ekg[32 * 64 + d];
      qekLoR += qv * ekg[d];
    }
  qekHiR += __shfl_xor(qekHiR, 32);
  qekLoR += __shfl_xor(qekLoR, 32);
  if (h == 0) qekL[w][l31][32] = f2bf(qekHiR);

  const int qg = q0w + l31;                   // this lane's q row
  f32x16 oaccL = {}, oaccH = {};              // O: col=d(lane), row=q(regs)
  float rsum = 0.f, wsHi = 0.f;

  for (int kt = 0; kt < 16; ++kt) {
    const int k0 = kt * 32;
    // swapped QK^T: A=K (row=key=l31), B=Q -> sacc col=q(lane), row=key(regs)
    f32x16 sacc = {};
    #pragma unroll
    for (int kk = 0; kk < 4; ++kk) {
      const short8 kf = *(const short8*)&Kg[qkb + (long)(k0 + l31) * HD + kk * 16 + h * 8];
      sacc = __builtin_amdgcn_mfma_f32_32x32x16_bf16(kf, qB[kk], sacc, 0, 0, 0);
    }
    // exp + bucket accounting (tile-class specialized; branch wave-uniform)
    const int dmin = k0 - q0w - 31, dmax = k0 + 31 - q0w;
    if (dmin >= MREL) {                       // all keys in hi bucket
      #pragma unroll
      for (int r = 0; r < 16; ++r) {
        const float p = __expf(sacc[r] + qekHiR);
        sacc[r] = p; rsum += p; wsHi += p;
      }
    } else if (dmax <= -MREL) {               // all keys in lo bucket
      #pragma unroll
      for (int r = 0; r < 16; ++r) {
        const float p = __expf(sacc[r] + qekLoR);
        sacc[r] = p; rsum += p;
      }
    } else {                                  // straddle: per-element gather
      #pragma unroll
      for (int r = 0; r < 16; ++r) {
        const int key = k0 + (r & 3) + 8 * (r >> 2) + 4 * h;
        const int db = key - qg;
        const int rcl = min(max(db, -MREL), MREL) + MREL;
        const float p = __expf(sacc[r] + bf2f(qekL[w][l31][rcl]));
        sacc[r] = p; rsum += p;
        if (db >= MREL)       wsHi += p;
        else if (db > -MREL)  wsmid[w][l31][db + MREL - 1] = f2bf(p);
      }
    }
    // pack + permlane swap -> PV A-frag (row=q, k=key); PV over 2 chunks
    #pragma unroll
    for (int c = 0; c < 2; ++c) {
      const int rb = c * 8;
      unsigned a0 = (unsigned)f2bf(sacc[rb + 0]) | ((unsigned)f2bf(sacc[rb + 1]) << 16);
      unsigned a1 = (unsigned)f2bf(sacc[rb + 2]) | ((unsigned)f2bf(sacc[rb + 3]) << 16);
      unsigned b0 = (unsigned)f2bf(sacc[rb + 4]) | ((unsigned)f2bf(sacc[rb + 5]) << 16);
      unsigned b1 = (unsigned)f2bf(sacc[rb + 6]) | ((unsigned)f2bf(sacc[rb + 7]) << 16);
      asm("v_permlane32_swap_b32 %0, %1" : "+v"(a0), "+v"(b0));
      asm("v_permlane32_swap_b32 %0, %1" : "+v"(a1), "+v"(b1));
      union { unsigned u[4]; short8 s; } pa;
      pa.u[0] = a0; pa.u[1] = a1; pa.u[2] = b0; pa.u[3] = b1;
      const short8 v0 = *(const short8*)&Vt[vtb + (long)l31 * SEQ + k0 + c * 16 + h * 8];
      const short8 v1 = *(const short8*)&Vt[vtb + (long)(32 + l31) * SEQ + k0 + c * 16 + h * 8];
      oaccL = __builtin_amdgcn_mfma_f32_32x32x16_bf16(pa.s, v0, oaccL, 0, 0, 0);
      oaccH = __builtin_amdgcn_mfma_f32_32x32x16_bf16(pa.s, v1, oaccH, 0, 0, 0);
    }
  }

  // ---- epilogue ----
  rsum += __shfl_xor(rsum, 32);
  wsHi += __shfl_xor(wsHi, 32);
  if (h == 0) { LROWw[w][l31] = rsum; WHIw[w][l31] = wsHi; }

  const int dl = l31;
  const float evLo0 = EVs[0][dl], evLo1 = EVs[0][dl + 32];
  const float evHi0 = EVs[32][dl], evHi1 = EVs[32][dl + 32];
  float mids[16];
  #pragma unroll
  for (int r = 0; r < 16; ++r) mids[r] = 0.f;
  for (int i = 1; i <= 31; ++i) {             // mid buckets
    const float e0 = EVs[i][dl], e1 = EVs[i][dl + 32];
    #pragma unroll
    for (int r = 0; r < 16; ++r) {
      const int qr = (r & 3) + 8 * (r >> 2) + 4 * h;
      const float m = bf2f(wsmid[w][qr][i - 1]);
      mids[r] += m;
      oaccL[r] += m * e0;
      oaccH[r] += m * e1;
    }
  }
  #pragma unroll
  for (int r = 0; r < 16; ++r) {
    const int qr = (r & 3) + 8 * (r >> 2) + 4 * h;
    const float rs = LROWw[w][qr];
    const float hi = WHIw[w][qr];
    const float lo = rs - hi - mids[r];
    const float rinv = 1.f / rs;
    const float oL = (oaccL[r] + hi * evHi0 + lo * evLo0) * rinv;
    const float oH = (oaccH[r] + hi * evHi1 + lo * evLo1) * rinv;
    const long orow = qkb + (long)(q0w + qr) * HD;
    Og[orow + dl] = f2bf(oL);
    Og[orow + dl + 32] = f2bf(oH);
  }
}

extern "C" void kernel_launch(void* const* d_in, const int* in_sizes, int n_in,
                              void* d_out, int out_size, void* d_ws, size_t ws_size,
                              hipStream_t stream) {
  const float* x    = (const float*)d_in[0];
  const int*   mask = (const int*)d_in[1];
  const float* dw_w = (const float*)d_in[2];
  const float* dw_b = (const float*)d_in[3];
  const float* pw_w = (const float*)d_in[4];
  const float* pw_b = (const float*)d_in[5];
  const float* lncg = (const float*)d_in[6];
  const float* lncb = (const float*)d_in[7];
  const float* wq   = (const float*)d_in[8];
  const float* bq   = (const float*)d_in[9];
  const float* wk   = (const float*)d_in[10];
  const float* bk   = (const float*)d_in[11];
  const float* wv   = (const float*)d_in[12];
  const float* bv   = (const float*)d_in[13];
  const float* wo   = (const float*)d_in[14];
  const float* bo   = (const float*)d_in[15];
  const float* ek   = (const float*)d_in[16];
  const float* ev   = (const float*)d_in[17];
  const float* lnag = (const float*)d_in[18];
  const float* lnab = (const float*)d_in[19];
  const float* wff  = (const float*)d_in[20];
  const float* bff  = (const float*)d_in[21];
  const float* lnfg = (const float*)d_in[22];
  const float* lnfb = (const float*)d_in[23];

  float* out = (float*)d_out;
  float* PE   = (float*)d_ws;                      // SEQ*HD f32
  float* NB32 = PE + SEQ * HD;                     // TOK*HD f32 (spare)
  ushortT* ABF = (ushortT*)(NB32 + (long)TOK * HD);// TOK*HD bf16 (activations)
  ushortT* QBF = ABF + (long)TOK * HD;
  ushortT* KBF = QBF + (long)TOK * HD;
  ushortT* VTB = KBF + (long)TOK * HD;             // V^T bf16 [b,h,d][s]
  ushortT* WBF = VTB + (long)TOK * HD;             // 7 * HD*HD bf16 weights
  const long WSZ = (long)HD * HD;

  pe_kernel<<<SEQ * HD / 256, 256, 0, stream>>>(PE);
  addpos_kernel<<<TOK * HD / 256, 256, 0, stream>>>(x, mask, PE, out);
  convw_kernel<<<7 * HD * HD / 4 / 256, 256, 0, stream>>>(
      pw_w, pw_w + WSZ, wq, wk, wv, wo, wff, WBF);

  for (int i = 0; i < 2; ++i) {
    ln_kernel<true><<<TOK, 256, 0, stream>>>(out, lncg + i * HD, lncb + i * HD, QBF);
    dwconv_kernel<<<TOK * HD / 256, 256, 0, stream>>>(QBF, dw_w + i * HD * 7, dw_b + i * HD, ABF);
    mgemm_kernel<2><<<512, 256, 0, stream>>>(ABF, WBF + i * WSZ, pw_b + i * HD, out, nullptr);
  }

  ln_kernel<true><<<TOK, 256, 0, stream>>>(out, lnag, lnab, ABF);
  mgemm_kernel<3><<<512, 256, 0, stream>>>(ABF, WBF + 2 * WSZ, bq, nullptr, QBF);
  mgemm_kernel<3><<<512, 256, 0, stream>>>(ABF, WBF + 3 * WSZ, bk, nullptr, KBF);
  mgemm_kernel<4><<<512, 256, 0, stream>>>(ABF, WBF + 4 * WSZ, bv, nullptr, VTB);
  attn_kernel<<<dim3(NHEAD, SEQ / 256, BATCH), 512, 0, stream>>>(QBF, KBF, VTB, ek, ev, ABF);
  mgemm_kernel<1><<<512, 256, 0, stream>>>(ABF, WBF + 5 * WSZ, bo, out, nullptr);

  ln_kernel<true><<<TOK, 256, 0, stream>>>(out, lnfg, lnfb, ABF);
  mgemm_kernel<2><<<512, 256, 0, stream>>>(ABF, WBF + 6 * WSZ, bff, out, nullptr);
}